// Round 1
// baseline (1038.695 us; speedup 1.0000x reference)
//
#include <hip/hip_runtime.h>
#include <hip/hip_bf16.h>
#include <cstdint>

typedef __hip_bfloat16 bf16;
typedef __attribute__((ext_vector_type(8))) short frag8;   // 8 bf16 (4 VGPRs) MFMA operand
typedef __attribute__((ext_vector_type(4))) float f32x4;   // MFMA accumulator

#define DEV __device__ __forceinline__

DEV void gl_lds16(const void* g, void* l) {
  __builtin_amdgcn_global_load_lds(
      (const __attribute__((address_space(1))) void*)g,
      (__attribute__((address_space(3))) void*)l, 16, 0, 0);
}

DEV void storeC(float* C, size_t idx, float v) { C[idx] = v; }
DEV void storeC(bf16* C, size_t idx, float v) { C[idx] = __float2bfloat16(v); }

// ---------------- f32 -> bf16 conversion, 8 elems/thread ----------------
__global__ __launch_bounds__(256) void conv_kernel(const float* __restrict__ in,
                                                   bf16* __restrict__ out, int n8) {
  int i = blockIdx.x * 256 + threadIdx.x;
  if (i >= n8) return;
  const float4* in4 = reinterpret_cast<const float4*>(in);
  float4 a = in4[2 * i], b = in4[2 * i + 1];
  union { frag8 v; bf16 h[8]; } u;
  u.h[0] = __float2bfloat16(a.x); u.h[1] = __float2bfloat16(a.y);
  u.h[2] = __float2bfloat16(a.z); u.h[3] = __float2bfloat16(a.w);
  u.h[4] = __float2bfloat16(b.x); u.h[5] = __float2bfloat16(b.y);
  u.h[6] = __float2bfloat16(b.z); u.h[7] = __float2bfloat16(b.w);
  *reinterpret_cast<frag8*>(out + (size_t)i * 8) = u.v;
}

// ---------------- GEMM: C[m,n] = sum_k A[m,k]*Bt[n,k]  (M=N=K=4096) ----------------
// m97 structure: 128x128 tile, BK=32, 4 waves (2x2), 16x16x32 bf16 MFMA,
// global_load_lds width=16 staging, 2 barriers per K-step.
template <typename OutT>
__global__ __launch_bounds__(256) void gemm_bt(const bf16* __restrict__ A,
                                               const bf16* __restrict__ Bt,
                                               OutT* __restrict__ C) {
  const int K = 4096, N = 4096;
  __shared__ bf16 As[128 * 32];
  __shared__ bf16 Bs[128 * 32];
  const int t = threadIdx.x;
  const int lane = t & 63, wid = t >> 6;
  const int wr = wid >> 1, wc = wid & 1;
  const int lr = lane & 15, lg = lane >> 4;
  const int m0 = blockIdx.y * 128, n0 = blockIdx.x * 128;

  const bf16* a0 = A + (size_t)(m0 + (t >> 2)) * K + (t & 3) * 8;
  const bf16* a1 = a0 + (size_t)64 * K;
  const bf16* b0 = Bt + (size_t)(n0 + (t >> 2)) * K + (t & 3) * 8;
  const bf16* b1 = b0 + (size_t)64 * K;
  bf16* lA0 = As + t * 8;
  bf16* lA1 = As + t * 8 + 2048;
  bf16* lB0 = Bs + t * 8;
  bf16* lB1 = Bs + t * 8 + 2048;

  f32x4 acc[4][4] = {};

  for (int k0 = 0; k0 < K; k0 += 32) {
    __syncthreads();
    gl_lds16(a0 + k0, lA0);
    gl_lds16(a1 + k0, lA1);
    gl_lds16(b0 + k0, lB0);
    gl_lds16(b1 + k0, lB1);
    __syncthreads();
    frag8 af[4], bfr[4];
#pragma unroll
    for (int mi = 0; mi < 4; ++mi)
      af[mi] = *reinterpret_cast<const frag8*>(&As[(wr * 64 + mi * 16 + lr) * 32 + lg * 8]);
#pragma unroll
    for (int ni = 0; ni < 4; ++ni)
      bfr[ni] = *reinterpret_cast<const frag8*>(&Bs[(wc * 64 + ni * 16 + lr) * 32 + lg * 8]);
#pragma unroll
    for (int mi = 0; mi < 4; ++mi)
#pragma unroll
      for (int ni = 0; ni < 4; ++ni)
        acc[mi][ni] = __builtin_amdgcn_mfma_f32_16x16x32_bf16(af[mi], bfr[ni], acc[mi][ni], 0, 0, 0);
  }

#pragma unroll
  for (int mi = 0; mi < 4; ++mi)
#pragma unroll
    for (int ni = 0; ni < 4; ++ni) {
      f32x4 v = acc[mi][ni];
      int col = n0 + wc * 64 + ni * 16 + lr;
#pragma unroll
      for (int i = 0; i < 4; ++i) {
        int row = m0 + wr * 64 + mi * 16 + lg * 4 + i;  // C/D: col=lane&15, row=(lane>>4)*4+i
        storeC(C, (size_t)row * N + col, v[i]);
      }
    }
}

// ---------------- RoPE (in-place on q,k; uses provided cos/sin tables) ----------------
// idx = ((b*1024+s)*32+h)*64 + i ; pair at element offset idx*2
__global__ __launch_bounds__(256) void rope_kernel(bf16* __restrict__ q, bf16* __restrict__ k,
                                                   const float* __restrict__ fc,
                                                   const float* __restrict__ fs) {
  int idx = blockIdx.x * 256 + threadIdx.x;
  int i = idx & 63;
  int s = (idx >> 11) & 1023;
  float c = fc[s * 64 + i], sn = fs[s * 64 + i];
  uint32_t* qp = reinterpret_cast<uint32_t*>(q) + idx;
  uint32_t* kp = reinterpret_cast<uint32_t*>(k) + idx;
  union { uint32_t u; bf16 h[2]; } a, r;
  a.u = *qp;
  {
    float x = __bfloat162float(a.h[0]), y = __bfloat162float(a.h[1]);
    r.h[0] = __float2bfloat16(x * c - y * sn);
    r.h[1] = __float2bfloat16(x * sn + y * c);
    *qp = r.u;
  }
  a.u = *kp;
  {
    float x = __bfloat162float(a.h[0]), y = __bfloat162float(a.h[1]);
    r.h[0] = __float2bfloat16(x * c - y * sn);
    r.h[1] = __float2bfloat16(x * sn + y * c);
    *kp = r.u;
  }
}

// ---------------- V transpose: v[b][s][h][d] -> vt[b][h][d][s] ----------------
__global__ __launch_bounds__(256) void transpose_v_kernel(const bf16* __restrict__ v,
                                                          bf16* __restrict__ vt) {
  __shared__ unsigned short tile[32][40];
  const int st = blockIdx.x * 32;
  const int dt = blockIdx.y * 32;
  const int bh = blockIdx.z;  // b*32+h
  const int b = bh >> 5, h = bh & 31;
  const int t = threadIdx.x;
  const int r = t >> 3, c4 = (t & 7) * 4;
  const unsigned short* src = reinterpret_cast<const unsigned short*>(v) +
      ((size_t)(b * 1024 + st + r)) * 4096 + h * 128 + dt + c4;
  uint2 d = *reinterpret_cast<const uint2*>(src);
  tile[r][c4 + 0] = (unsigned short)(d.x & 0xffff);
  tile[r][c4 + 1] = (unsigned short)(d.x >> 16);
  tile[r][c4 + 2] = (unsigned short)(d.y & 0xffff);
  tile[r][c4 + 3] = (unsigned short)(d.y >> 16);
  __syncthreads();
  uint2 o;
  o.x = (uint32_t)tile[c4 + 0][r] | ((uint32_t)tile[c4 + 1][r] << 16);
  o.y = (uint32_t)tile[c4 + 2][r] | ((uint32_t)tile[c4 + 3][r] << 16);
  unsigned short* dst = reinterpret_cast<unsigned short*>(vt) +
      ((size_t)bh * 128 + dt + r) * 1024 + st + c4;
  *reinterpret_cast<uint2*>(dst) = o;
}

// ---------------- Flash attention: q,k [b][s][h][d] bf16, vt [b][h][d][s] bf16 ----------------
// block = 64 q-rows for one (b,h); 4 waves x 16 rows; KV tiles of 64, online softmax.
// All LDS tiles XOR-swizzled (byte ^= (row&7)<<4) via pre-swizzled global source (G4/m201 pattern).
__global__ __launch_bounds__(256) void attn_kernel(const bf16* __restrict__ q,
                                                   const bf16* __restrict__ k,
                                                   const bf16* __restrict__ vt,
                                                   bf16* __restrict__ out) {
  __shared__ bf16 Kls[64 * 128];   // rows 256B, swizzled
  __shared__ bf16 Vls[128 * 64];   // rows 128B (d-major), swizzled
  __shared__ bf16 Pls[4][16 * 64]; // per-wave P strip, rows 128B, swizzled
  const int qt = blockIdx.x, h = blockIdx.y, b = blockIdx.z;
  const int t = threadIdx.x;
  const int lane = t & 63, wid = t >> 6;
  const int lr = lane & 15, lg = lane >> 4;

  // Q fragments (A-operand): row=lane&15, k=(lane>>4)*8+e
  frag8 aq[4];
  {
    const bf16* qp = q + ((size_t)(b * 1024 + qt * 64 + wid * 16 + lr)) * 4096 + h * 128 + lg * 8;
#pragma unroll
    for (int ks = 0; ks < 4; ++ks) aq[ks] = *reinterpret_cast<const frag8*>(qp + ks * 32);
  }

  const bf16* kbase = k + (size_t)b * 1024 * 4096 + h * 128;
  const bf16* vbase = vt + ((size_t)(b * 32 + h)) * 128 * 1024;
  const bf16* ksrc[4]; const bf16* vsrc[4]; char* kdst[4]; char* vdst[4];
#pragma unroll
  for (int c = 0; c < 4; ++c) {
    int L = t * 16 + c * 4096;
    int kr = L >> 8, kc = (L & 255) ^ ((kr & 7) << 4);
    ksrc[c] = kbase + (size_t)kr * 4096 + (kc >> 1);
    kdst[c] = (char*)Kls + L;
    int vr = L >> 7, vc = (L & 127) ^ ((vr & 7) << 4);
    vsrc[c] = vbase + (size_t)vr * 1024 + (vc >> 1);
    vdst[c] = (char*)Vls + L;
  }

  f32x4 oacc[8] = {};
  float mrow[4] = {-1e30f, -1e30f, -1e30f, -1e30f};
  float lrow[4] = {0.f, 0.f, 0.f, 0.f};
  char* Pw = (char*)&Pls[wid][0];
  const float scale = 0.08838834764831845f;  // 1/sqrt(128)

  for (int kt = 0; kt <= qt; ++kt) {
    __syncthreads();
#pragma unroll
    for (int c = 0; c < 4; ++c) {
      gl_lds16(ksrc[c] + (size_t)kt * 262144, kdst[c]);
      gl_lds16(vsrc[c] + kt * 64, vdst[c]);
    }
    __syncthreads();

    // S = Q K^T over HD=128 (4 k-steps)
    f32x4 sacc[4] = {};
#pragma unroll
    for (int ks = 0; ks < 4; ++ks) {
#pragma unroll
      for (int ni = 0; ni < 4; ++ni) {
        int n = ni * 16 + lr;
        frag8 bk = *reinterpret_cast<const frag8*>(
            (const char*)Kls + n * 256 + ((ks * 64 + lg * 16) ^ ((n & 7) << 4)));
        sacc[ni] = __builtin_amdgcn_mfma_f32_16x16x32_bf16(aq[ks], bk, sacc[ni], 0, 0, 0);
      }
    }

    float sv[4][4];
#pragma unroll
    for (int ni = 0; ni < 4; ++ni)
#pragma unroll
      for (int i = 0; i < 4; ++i) {
        float x = sacc[ni][i] * scale;
        if (kt == qt) {
          int qr = wid * 16 + lg * 4 + i;
          int kc = ni * 16 + lr;
          if (kc > qr) x = -1e30f;
        }
        sv[ni][i] = x;
      }

    // online softmax (rows owned per quarter-wave group; reduce across 16 lanes)
    float fs_[4];
#pragma unroll
    for (int i = 0; i < 4; ++i) {
      float pm = fmaxf(fmaxf(sv[0][i], sv[1][i]), fmaxf(sv[2][i], sv[3][i]));
#pragma unroll
      for (int m = 1; m <= 8; m <<= 1) pm = fmaxf(pm, __shfl_xor(pm, m));
      float mn = fmaxf(mrow[i], pm);
      float f = __expf(mrow[i] - mn);
      float rs = 0.f;
#pragma unroll
      for (int ni = 0; ni < 4; ++ni) {
        float p = __expf(sv[ni][i] - mn);
        sv[ni][i] = p;
        rs += p;
      }
#pragma unroll
      for (int m = 1; m <= 8; m <<= 1) rs += __shfl_xor(rs, m);
      lrow[i] = lrow[i] * f + rs;
      mrow[i] = mn;
      fs_[i] = f;
    }
#pragma unroll
    for (int nj = 0; nj < 8; ++nj)
#pragma unroll
      for (int i = 0; i < 4; ++i) oacc[nj][i] *= fs_[i];

    // P -> LDS (bf16, swizzled, wave-private strip)
#pragma unroll
    for (int ni = 0; ni < 4; ++ni)
#pragma unroll
      for (int i = 0; i < 4; ++i) {
        int prow = lg * 4 + i;
        int pb = prow * 128 + (((ni * 16 + lr) * 2) ^ ((prow & 7) << 4));
        *reinterpret_cast<bf16*>(Pw + pb) = __float2bfloat16(sv[ni][i]);
      }

    // O += P V  (kv in 2 k-steps of 32)
#pragma unroll
    for (int ks2 = 0; ks2 < 2; ++ks2) {
      frag8 ap = *reinterpret_cast<const frag8*>(
          Pw + lr * 128 + ((ks2 * 64 + lg * 16) ^ ((lr & 7) << 4)));
#pragma unroll
      for (int nj = 0; nj < 8; ++nj) {
        int d = nj * 16 + lr;
        frag8 bv = *reinterpret_cast<const frag8*>(
            (const char*)Vls + d * 128 + ((ks2 * 64 + lg * 16) ^ ((d & 7) << 4)));
        oacc[nj] = __builtin_amdgcn_mfma_f32_16x16x32_bf16(ap, bv, oacc[nj], 0, 0, 0);
      }
    }
  }

  // normalize + write (b,s,h,d) bf16
#pragma unroll
  for (int nj = 0; nj < 8; ++nj)
#pragma unroll
    for (int i = 0; i < 4; ++i) {
      int srow = qt * 64 + wid * 16 + lg * 4 + i;
      out[((size_t)(b * 1024 + srow)) * 4096 + h * 128 + nj * 16 + lr] =
          __float2bfloat16(oacc[nj][i] / lrow[i]);
    }
}

// ---------------- host launch ----------------
extern "C" void kernel_launch(void* const* d_in, const int* in_sizes, int n_in,
                              void* d_out, int out_size, void* d_ws, size_t ws_size,
                              hipStream_t stream) {
  const float* x  = (const float*)d_in[0];
  const float* fc = (const float*)d_in[2];
  const float* fs = (const float*)d_in[3];
  const float* wq = (const float*)d_in[5];
  const float* wk = (const float*)d_in[6];
  const float* wv = (const float*)d_in[7];
  const float* wo = (const float*)d_in[8];
  float* out = (float*)d_out;

  const size_t SZ = (size_t)4096 * 4096 * 2;  // 33.5 MB per bf16 matrix; total ws use = 5*SZ = 168 MB
  char* w = (char*)d_ws;
  bf16* xb = (bf16*)(w);
  bf16* wb = (bf16*)(w + SZ);
  bf16* qb = (bf16*)(w + 2 * SZ);
  bf16* kb = (bf16*)(w + 3 * SZ);
  bf16* vb = (bf16*)(w + 4 * SZ);
  bf16* vtb = xb;  // xb dead after QKV GEMMs
  bf16* ao  = vb;  // vb dead after transpose

  const int n8 = 4096 * 4096 / 8;
  dim3 cgrd(n8 / 256), blk(256);
  dim3 ggrd(32, 32);

  conv_kernel<<<cgrd, blk, 0, stream>>>(x, xb, n8);
  conv_kernel<<<cgrd, blk, 0, stream>>>(wq, wb, n8);
  gemm_bt<bf16><<<ggrd, blk, 0, stream>>>(xb, wb, qb);
  conv_kernel<<<cgrd, blk, 0, stream>>>(wk, wb, n8);
  gemm_bt<bf16><<<ggrd, blk, 0, stream>>>(xb, wb, kb);
  conv_kernel<<<cgrd, blk, 0, stream>>>(wv, wb, n8);
  gemm_bt<bf16><<<ggrd, blk, 0, stream>>>(xb, wb, vb);
  rope_kernel<<<dim3(32768), blk, 0, stream>>>(qb, kb, fc, fs);
  transpose_v_kernel<<<dim3(32, 4, 128), blk, 0, stream>>>(vb, vtb);
  attn_kernel<<<dim3(16, 32, 4), blk, 0, stream>>>(qb, kb, vtb, ao);
  conv_kernel<<<cgrd, blk, 0, stream>>>(wo, wb, n8);
  gemm_bt<float><<<ggrd, blk, 0, stream>>>(ao, wb, out);
}

// Round 2
// 749.345 us; speedup vs baseline: 1.3861x; 1.3861x over previous
//
#include <hip/hip_runtime.h>
#include <hip/hip_bf16.h>
#include <cstdint>

typedef __hip_bfloat16 bf16;
typedef __attribute__((ext_vector_type(8))) short frag8;   // 8 bf16 (4 VGPRs) MFMA operand
typedef __attribute__((ext_vector_type(4))) float f32x4;   // MFMA accumulator

#define DEV __device__ __forceinline__

DEV void gl_lds16(const void* g, void* l) {
  __builtin_amdgcn_global_load_lds(
      (const __attribute__((address_space(1))) void*)g,
      (__attribute__((address_space(3))) void*)l, 16, 0, 0);
}

DEV void storeC(float* C, size_t idx, float v) { C[idx] = v; }
DEV void storeC(bf16* C, size_t idx, float v) { C[idx] = __float2bfloat16(v); }

// ---------------- f32 -> bf16 conversion, 8 elems/thread ----------------
__global__ __launch_bounds__(256) void conv_kernel(const float* __restrict__ in,
                                                   bf16* __restrict__ out, int n8) {
  int i = blockIdx.x * 256 + threadIdx.x;
  if (i >= n8) return;
  const float4* in4 = reinterpret_cast<const float4*>(in);
  float4 a = in4[2 * i], b = in4[2 * i + 1];
  union { frag8 v; bf16 h[8]; } u;
  u.h[0] = __float2bfloat16(a.x); u.h[1] = __float2bfloat16(a.y);
  u.h[2] = __float2bfloat16(a.z); u.h[3] = __float2bfloat16(a.w);
  u.h[4] = __float2bfloat16(b.x); u.h[5] = __float2bfloat16(b.y);
  u.h[6] = __float2bfloat16(b.z); u.h[7] = __float2bfloat16(b.w);
  *reinterpret_cast<frag8*>(out + (size_t)i * 8) = u.v;
}

// ---------------- GEMM (8-phase 256^2, BK=64, 8 waves): C = A * Bt^T ----------------
// LDS (128 KiB): A: [buf][half][128][64] bf16 at byte (buf*2+half)<<14; B same at +65536.
// Swizzle: byte_in_row ^= (row&7)<<4, applied on BOTH the ds_read address and the
// pre-swizzled global source of global_load_lds (linear LDS dest).
#define MF(a, b, c) __builtin_amdgcn_mfma_f32_16x16x32_bf16(a, b, c, 0, 0, 0)

#define STAGE(isB, h, tt, bp) do {                                             \
    char* _d = lds + ((isB) * 65536) + ((((bp) * 2) + (h)) << 14);             \
    gl_lds16(((isB) ? gB : gA)[h][0] + (size_t)(tt) * 64, _d + ldsOff0);       \
    gl_lds16(((isB) ? gB : gA)[h][1] + (size_t)(tt) * 64, _d + ldsOff1);       \
  } while (0)

#define RDA(mi, ckk) (*(const frag8*)(ab + aRowB + (mi) * 2048 + (ckk)))
#define RDB(ni, ckk) (*(const frag8*)(bb + bRowB + (ni) * 2048 + (ckk)))

#define PHASE(p, SSTAGE, SWAIT) do {                                           \
    if ((p) == 0) {                                                            \
      b00 = RDB(0, ck0); b01 = RDB(0, ck1); b10 = RDB(1, ck0); b11 = RDB(1, ck1); \
      b20 = RDB(2, ck0); b21 = RDB(2, ck1); b30 = RDB(3, ck0); b31 = RDB(3, ck1); \
    }                                                                          \
    frag8 a00 = RDA(2 * (p), ck0), a01 = RDA(2 * (p), ck1);                    \
    frag8 a10 = RDA(2 * (p) + 1, ck0), a11 = RDA(2 * (p) + 1, ck1);            \
    SSTAGE;                                                                    \
    SWAIT;                                                                     \
    __builtin_amdgcn_s_barrier();                                              \
    __builtin_amdgcn_s_setprio(1);                                             \
    acc[2*(p)][0]   = MF(a00, b00, acc[2*(p)][0]);                             \
    acc[2*(p)][1]   = MF(a00, b10, acc[2*(p)][1]);                             \
    acc[2*(p)][2]   = MF(a00, b20, acc[2*(p)][2]);                             \
    acc[2*(p)][3]   = MF(a00, b30, acc[2*(p)][3]);                             \
    acc[2*(p)+1][0] = MF(a10, b00, acc[2*(p)+1][0]);                           \
    acc[2*(p)+1][1] = MF(a10, b10, acc[2*(p)+1][1]);                           \
    acc[2*(p)+1][2] = MF(a10, b20, acc[2*(p)+1][2]);                           \
    acc[2*(p)+1][3] = MF(a10, b30, acc[2*(p)+1][3]);                           \
    acc[2*(p)][0]   = MF(a01, b01, acc[2*(p)][0]);                             \
    acc[2*(p)][1]   = MF(a01, b11, acc[2*(p)][1]);                             \
    acc[2*(p)][2]   = MF(a01, b21, acc[2*(p)][2]);                             \
    acc[2*(p)][3]   = MF(a01, b31, acc[2*(p)][3]);                             \
    acc[2*(p)+1][0] = MF(a11, b01, acc[2*(p)+1][0]);                           \
    acc[2*(p)+1][1] = MF(a11, b11, acc[2*(p)+1][1]);                           \
    acc[2*(p)+1][2] = MF(a11, b21, acc[2*(p)+1][2]);                           \
    acc[2*(p)+1][3] = MF(a11, b31, acc[2*(p)+1][3]);                           \
    __builtin_amdgcn_s_setprio(0);                                             \
    __builtin_amdgcn_s_barrier();                                              \
  } while (0)

#define VM4 asm volatile("s_waitcnt vmcnt(4)" ::: "memory")
#define VM0 asm volatile("s_waitcnt vmcnt(0)" ::: "memory")
#define NOW ((void)0)

#define TILE(t, SA, SB, SWAIT) do {                                            \
    const int _bp2 = ((t) & 1) * 2;                                            \
    char* ab = lds + ((_bp2 + wm) << 14);                                      \
    char* bb = lds + 65536 + ((_bp2 + bhalf) << 14);                           \
    PHASE(0, { if (SA) STAGE(0, 0, (t) + 1, ((t) + 1) & 1); }, NOW);           \
    PHASE(1, { if (SA) STAGE(0, 1, (t) + 1, ((t) + 1) & 1); }, NOW);           \
    PHASE(2, { if (SB) STAGE(1, 0, (t) + 2, (t) & 1); }, NOW);                 \
    PHASE(3, { if (SB) STAGE(1, 1, (t) + 2, (t) & 1); }, SWAIT);               \
  } while (0)

template <typename OutT>
__global__ __launch_bounds__(512, 2) void gemm8(const bf16* __restrict__ A,
                                                const bf16* __restrict__ Bt,
                                                OutT* __restrict__ C) {
  __shared__ __align__(16) char lds[131072];
  const int K = 4096, N = 4096;
  const int t = threadIdx.x;
  const int lane = t & 63, w = t >> 6;
  const int wm = w >> 2, wn = w & 3;   // 2 M-waves x 4 N-waves
  const int lr = lane & 15, lg = lane >> 4;
  const int bhalf = wn >> 1;

  // bijective XCD swizzle (256 blocks, 8 XCDs -> 32 contiguous tiles each)
  const int bid = blockIdx.x;
  const int wg = (bid & 7) * 32 + (bid >> 3);
  const int m0 = (wg >> 4) * 256, n0 = (wg & 15) * 256;

  // staging precompute: 2 chunks/thread per half-tile (16 KiB half = 1024 x 16B)
  const bf16* gA[2][2];
  const bf16* gB[2][2];
  int ldsOff0, ldsOff1;
  {
    int c0 = (w * 2 + 0) * 64 + lane;
    int c1 = (w * 2 + 1) * 64 + lane;
    int r0 = c0 >> 3, r1 = c1 >> 3;
    int e0 = ((c0 & 7) ^ (r0 & 7)) * 8;   // inverse-swizzled source column (elems)
    int e1 = ((c1 & 7) ^ (r1 & 7)) * 8;
    ldsOff0 = c0 * 16; ldsOff1 = c1 * 16;
    gA[0][0] = A + (size_t)(m0 + r0) * K + e0;
    gA[0][1] = A + (size_t)(m0 + r1) * K + e1;
    gA[1][0] = A + (size_t)(m0 + 128 + r0) * K + e0;
    gA[1][1] = A + (size_t)(m0 + 128 + r1) * K + e1;
    gB[0][0] = Bt + (size_t)(n0 + r0) * K + e0;
    gB[0][1] = Bt + (size_t)(n0 + r1) * K + e1;
    gB[1][0] = Bt + (size_t)(n0 + 128 + r0) * K + e0;
    gB[1][1] = Bt + (size_t)(n0 + 128 + r1) * K + e1;
  }

  // ds_read address constants (swizzled)
  const int swz = (lr & 7) << 4;
  const int ck0 = (lg * 16) ^ swz;        // kk=0
  const int ck1 = (64 + lg * 16) ^ swz;   // kk=1
  const int aRowB = lr * 128;
  const int bRowB = ((wn & 1) * 64 + lr) * 128;

  f32x4 acc[8][4];
#pragma unroll
  for (int mi = 0; mi < 8; ++mi)
#pragma unroll
    for (int ni = 0; ni < 4; ++ni) acc[mi][ni] = (f32x4){0.f, 0.f, 0.f, 0.f};

  frag8 b00, b01, b10, b11, b20, b21, b30, b31;

  // prologue: B0(0),B1(0),A0(0),A1(0),B0(1),B1(1) then counted drain (tile 0 landed)
  STAGE(1, 0, 0, 0); STAGE(1, 1, 0, 0);
  STAGE(0, 0, 0, 0); STAGE(0, 1, 0, 0);
  STAGE(1, 0, 1, 1); STAGE(1, 1, 1, 1);
  VM4;
  __builtin_amdgcn_s_barrier();

  for (int tt = 0; tt < 62; tt += 2) {
    TILE(tt, 1, 1, VM4);
    TILE(tt + 1, 1, 1, VM4);
  }
  TILE(62, 1, 0, VM0);
  TILE(63, 0, 0, NOW);

  // epilogue: C/D layout col=lane&15, row=(lane>>4)*4+i
#pragma unroll
  for (int mi = 0; mi < 8; ++mi)
#pragma unroll
    for (int ni = 0; ni < 4; ++ni) {
      f32x4 v = acc[mi][ni];
      int col = n0 + wn * 64 + ni * 16 + lr;
#pragma unroll
      for (int i = 0; i < 4; ++i) {
        int row = m0 + wm * 128 + mi * 16 + lg * 4 + i;
        storeC(C, (size_t)row * N + col, v[i]);
      }
    }
}

// ---------------- RoPE (in-place on q,k; uses provided cos/sin tables) ----------------
__global__ __launch_bounds__(256) void rope_kernel(bf16* __restrict__ q, bf16* __restrict__ k,
                                                   const float* __restrict__ fc,
                                                   const float* __restrict__ fs) {
  int idx = blockIdx.x * 256 + threadIdx.x;
  int i = idx & 63;
  int s = (idx >> 11) & 1023;
  float c = fc[s * 64 + i], sn = fs[s * 64 + i];
  uint32_t* qp = reinterpret_cast<uint32_t*>(q) + idx;
  uint32_t* kp = reinterpret_cast<uint32_t*>(k) + idx;
  union { uint32_t u; bf16 h[2]; } a, r;
  a.u = *qp;
  {
    float x = __bfloat162float(a.h[0]), y = __bfloat162float(a.h[1]);
    r.h[0] = __float2bfloat16(x * c - y * sn);
    r.h[1] = __float2bfloat16(x * sn + y * c);
    *qp = r.u;
  }
  a.u = *kp;
  {
    float x = __bfloat162float(a.h[0]), y = __bfloat162float(a.h[1]);
    r.h[0] = __float2bfloat16(x * c - y * sn);
    r.h[1] = __float2bfloat16(x * sn + y * c);
    *kp = r.u;
  }
}

// ---------------- V transpose: v[b][s][h][d] -> vt[b][h][d][s] ----------------
__global__ __launch_bounds__(256) void transpose_v_kernel(const bf16* __restrict__ v,
                                                          bf16* __restrict__ vt) {
  __shared__ unsigned short tile[32][40];
  const int st = blockIdx.x * 32;
  const int dt = blockIdx.y * 32;
  const int bh = blockIdx.z;  // b*32+h
  const int b = bh >> 5, h = bh & 31;
  const int t = threadIdx.x;
  const int r = t >> 3, c4 = (t & 7) * 4;
  const unsigned short* src = reinterpret_cast<const unsigned short*>(v) +
      ((size_t)(b * 1024 + st + r)) * 4096 + h * 128 + dt + c4;
  uint2 d = *reinterpret_cast<const uint2*>(src);
  tile[r][c4 + 0] = (unsigned short)(d.x & 0xffff);
  tile[r][c4 + 1] = (unsigned short)(d.x >> 16);
  tile[r][c4 + 2] = (unsigned short)(d.y & 0xffff);
  tile[r][c4 + 3] = (unsigned short)(d.y >> 16);
  __syncthreads();
  uint2 o;
  o.x = (uint32_t)tile[c4 + 0][r] | ((uint32_t)tile[c4 + 1][r] << 16);
  o.y = (uint32_t)tile[c4 + 2][r] | ((uint32_t)tile[c4 + 3][r] << 16);
  unsigned short* dst = reinterpret_cast<unsigned short*>(vt) +
      ((size_t)bh * 128 + dt + r) * 1024 + st + c4;
  *reinterpret_cast<uint2*>(dst) = o;
}

// ---------------- Flash attention (unchanged from R0, verified) ----------------
__global__ __launch_bounds__(256) void attn_kernel(const bf16* __restrict__ q,
                                                   const bf16* __restrict__ k,
                                                   const bf16* __restrict__ vt,
                                                   bf16* __restrict__ out) {
  __shared__ bf16 Kls[64 * 128];
  __shared__ bf16 Vls[128 * 64];
  __shared__ bf16 Pls[4][16 * 64];
  const int qt = blockIdx.x, h = blockIdx.y, b = blockIdx.z;
  const int t = threadIdx.x;
  const int lane = t & 63, wid = t >> 6;
  const int lr = lane & 15, lg = lane >> 4;

  frag8 aq[4];
  {
    const bf16* qp = q + ((size_t)(b * 1024 + qt * 64 + wid * 16 + lr)) * 4096 + h * 128 + lg * 8;
#pragma unroll
    for (int ks = 0; ks < 4; ++ks) aq[ks] = *reinterpret_cast<const frag8*>(qp + ks * 32);
  }

  const bf16* kbase = k + (size_t)b * 1024 * 4096 + h * 128;
  const bf16* vbase = vt + ((size_t)(b * 32 + h)) * 128 * 1024;
  const bf16* ksrc[4]; const bf16* vsrc[4]; char* kdst[4]; char* vdst[4];
#pragma unroll
  for (int c = 0; c < 4; ++c) {
    int L = t * 16 + c * 4096;
    int kr = L >> 8, kc = (L & 255) ^ ((kr & 7) << 4);
    ksrc[c] = kbase + (size_t)kr * 4096 + (kc >> 1);
    kdst[c] = (char*)Kls + L;
    int vr = L >> 7, vc = (L & 127) ^ ((vr & 7) << 4);
    vsrc[c] = vbase + (size_t)vr * 1024 + (vc >> 1);
    vdst[c] = (char*)Vls + L;
  }

  f32x4 oacc[8] = {};
  float mrow[4] = {-1e30f, -1e30f, -1e30f, -1e30f};
  float lrow[4] = {0.f, 0.f, 0.f, 0.f};
  char* Pw = (char*)&Pls[wid][0];
  const float scale = 0.08838834764831845f;

  for (int kt = 0; kt <= qt; ++kt) {
    __syncthreads();
#pragma unroll
    for (int c = 0; c < 4; ++c) {
      gl_lds16(ksrc[c] + (size_t)kt * 262144, kdst[c]);
      gl_lds16(vsrc[c] + kt * 64, vdst[c]);
    }
    __syncthreads();

    f32x4 sacc[4] = {};
#pragma unroll
    for (int ks = 0; ks < 4; ++ks) {
#pragma unroll
      for (int ni = 0; ni < 4; ++ni) {
        int n = ni * 16 + lr;
        frag8 bk = *reinterpret_cast<const frag8*>(
            (const char*)Kls + n * 256 + ((ks * 64 + lg * 16) ^ ((n & 7) << 4)));
        sacc[ni] = __builtin_amdgcn_mfma_f32_16x16x32_bf16(aq[ks], bk, sacc[ni], 0, 0, 0);
      }
    }

    float sv[4][4];
#pragma unroll
    for (int ni = 0; ni < 4; ++ni)
#pragma unroll
      for (int i = 0; i < 4; ++i) {
        float x = sacc[ni][i] * scale;
        if (kt == qt) {
          int qr = wid * 16 + lg * 4 + i;
          int kc = ni * 16 + lr;
          if (kc > qr) x = -1e30f;
        }
        sv[ni][i] = x;
      }

    float fs_[4];
#pragma unroll
    for (int i = 0; i < 4; ++i) {
      float pm = fmaxf(fmaxf(sv[0][i], sv[1][i]), fmaxf(sv[2][i], sv[3][i]));
#pragma unroll
      for (int m = 1; m <= 8; m <<= 1) pm = fmaxf(pm, __shfl_xor(pm, m));
      float mn = fmaxf(mrow[i], pm);
      float f = __expf(mrow[i] - mn);
      float rs = 0.f;
#pragma unroll
      for (int ni = 0; ni < 4; ++ni) {
        float p = __expf(sv[ni][i] - mn);
        sv[ni][i] = p;
        rs += p;
      }
#pragma unroll
      for (int m = 1; m <= 8; m <<= 1) rs += __shfl_xor(rs, m);
      lrow[i] = lrow[i] * f + rs;
      mrow[i] = mn;
      fs_[i] = f;
    }
#pragma unroll
    for (int nj = 0; nj < 8; ++nj)
#pragma unroll
      for (int i = 0; i < 4; ++i) oacc[nj][i] *= fs_[i];

#pragma unroll
    for (int ni = 0; ni < 4; ++ni)
#pragma unroll
      for (int i = 0; i < 4; ++i) {
        int prow = lg * 4 + i;
        int pb = prow * 128 + (((ni * 16 + lr) * 2) ^ ((prow & 7) << 4));
        *reinterpret_cast<bf16*>(Pw + pb) = __float2bfloat16(sv[ni][i]);
      }

#pragma unroll
    for (int ks2 = 0; ks2 < 2; ++ks2) {
      frag8 ap = *reinterpret_cast<const frag8*>(
          Pw + lr * 128 + ((ks2 * 64 + lg * 16) ^ ((lr & 7) << 4)));
#pragma unroll
      for (int nj = 0; nj < 8; ++nj) {
        int d = nj * 16 + lr;
        frag8 bv = *reinterpret_cast<const frag8*>(
            (const char*)Vls + d * 128 + ((ks2 * 64 + lg * 16) ^ ((d & 7) << 4)));
        oacc[nj] = __builtin_amdgcn_mfma_f32_16x16x32_bf16(ap, bv, oacc[nj], 0, 0, 0);
      }
    }
  }

#pragma unroll
  for (int nj = 0; nj < 8; ++nj)
#pragma unroll
    for (int i = 0; i < 4; ++i) {
      int srow = qt * 64 + wid * 16 + lg * 4 + i;
      out[((size_t)(b * 1024 + srow)) * 4096 + h * 128 + nj * 16 + lr] =
          __float2bfloat16(oacc[nj][i] / lrow[i]);
    }
}

// ---------------- host launch ----------------
extern "C" void kernel_launch(void* const* d_in, const int* in_sizes, int n_in,
                              void* d_out, int out_size, void* d_ws, size_t ws_size,
                              hipStream_t stream) {
  const float* x  = (const float*)d_in[0];
  const float* fc = (const float*)d_in[2];
  const float* fs = (const float*)d_in[3];
  const float* wq = (const float*)d_in[5];
  const float* wk = (const float*)d_in[6];
  const float* wv = (const float*)d_in[7];
  const float* wo = (const float*)d_in[8];
  float* out = (float*)d_out;

  const size_t SZ = (size_t)4096 * 4096 * 2;
  char* w = (char*)d_ws;
  bf16* xb = (bf16*)(w);
  bf16* wb = (bf16*)(w + SZ);
  bf16* qb = (bf16*)(w + 2 * SZ);
  bf16* kb = (bf16*)(w + 3 * SZ);
  bf16* vb = (bf16*)(w + 4 * SZ);
  bf16* vtb = xb;  // xb dead after QKV GEMMs
  bf16* ao  = vb;  // vb dead after transpose

  const int n8 = 4096 * 4096 / 8;
  dim3 cgrd(n8 / 256), blk(256);
  dim3 ggrd(256);
  dim3 gblk(512);

  conv_kernel<<<cgrd, blk, 0, stream>>>(x, xb, n8);
  conv_kernel<<<cgrd, blk, 0, stream>>>(wq, wb, n8);
  gemm8<bf16><<<ggrd, gblk, 0, stream>>>(xb, wb, qb);
  conv_kernel<<<cgrd, blk, 0, stream>>>(wk, wb, n8);
  gemm8<bf16><<<ggrd, gblk, 0, stream>>>(xb, wb, kb);
  conv_kernel<<<cgrd, blk, 0, stream>>>(wv, wb, n8);
  gemm8<bf16><<<ggrd, gblk, 0, stream>>>(xb, wb, vb);
  rope_kernel<<<dim3(32768), blk, 0, stream>>>(qb, kb, fc, fs);
  transpose_v_kernel<<<dim3(32, 4, 128), blk, 0, stream>>>(vb, vtb);
  attn_kernel<<<dim3(16, 32, 4), blk, 0, stream>>>(qb, kb, vtb, ao);
  conv_kernel<<<cgrd, blk, 0, stream>>>(wo, wb, n8);
  gemm8<float><<<ggrd, gblk, 0, stream>>>(ao, wb, out);
}

// Round 3
// 712.337 us; speedup vs baseline: 1.4582x; 1.0520x over previous
//
#include <hip/hip_runtime.h>
#include <hip/hip_bf16.h>
#include <cstdint>

typedef __hip_bfloat16 bf16;
typedef __attribute__((ext_vector_type(8))) short frag8;   // 8 bf16 (4 VGPRs) MFMA operand
typedef __attribute__((ext_vector_type(4))) float f32x4;   // MFMA accumulator

#define DEV __device__ __forceinline__

DEV void gl_lds16(const void* g, void* l) {
  __builtin_amdgcn_global_load_lds(
      (const __attribute__((address_space(1))) void*)g,
      (__attribute__((address_space(3))) void*)l, 16, 0, 0);
}

DEV void storeC(float* C, size_t idx, float v) { C[idx] = v; }
DEV void storeC(bf16* C, size_t idx, float v) { C[idx] = __float2bfloat16(v); }

// ---------------- f32 -> bf16 conversion, 8 elems/thread ----------------
__global__ __launch_bounds__(256) void conv_kernel(const float* __restrict__ in,
                                                   bf16* __restrict__ out, int n8) {
  int i = blockIdx.x * 256 + threadIdx.x;
  if (i >= n8) return;
  const float4* in4 = reinterpret_cast<const float4*>(in);
  float4 a = in4[2 * i], b = in4[2 * i + 1];
  union { frag8 v; bf16 h[8]; } u;
  u.h[0] = __float2bfloat16(a.x); u.h[1] = __float2bfloat16(a.y);
  u.h[2] = __float2bfloat16(a.z); u.h[3] = __float2bfloat16(a.w);
  u.h[4] = __float2bfloat16(b.x); u.h[5] = __float2bfloat16(b.y);
  u.h[6] = __float2bfloat16(b.z); u.h[7] = __float2bfloat16(b.w);
  *reinterpret_cast<frag8*>(out + (size_t)i * 8) = u.v;
}

// ---------------- GEMM (8-phase 256^2, BK=64, 8 waves): C = A * Bt^T ----------------
#define MF(a, b, c) __builtin_amdgcn_mfma_f32_16x16x32_bf16(a, b, c, 0, 0, 0)

#define STAGE(isB, h, tt, bp) do {                                             \
    char* _d = lds + ((isB) * 65536) + ((((bp) * 2) + (h)) << 14);             \
    gl_lds16(((isB) ? gB : gA)[h][0] + (size_t)(tt) * 64, _d + ldsOff0);       \
    gl_lds16(((isB) ? gB : gA)[h][1] + (size_t)(tt) * 64, _d + ldsOff1);       \
  } while (0)

#define RDA(mi, ckk) (*(const frag8*)(ab + aRowB + (mi) * 2048 + (ckk)))
#define RDB(ni, ckk) (*(const frag8*)(bb + bRowB + (ni) * 2048 + (ckk)))

#define PHASE(p, SSTAGE, SWAIT) do {                                           \
    if ((p) == 0) {                                                            \
      b00 = RDB(0, ck0); b01 = RDB(0, ck1); b10 = RDB(1, ck0); b11 = RDB(1, ck1); \
      b20 = RDB(2, ck0); b21 = RDB(2, ck1); b30 = RDB(3, ck0); b31 = RDB(3, ck1); \
    }                                                                          \
    frag8 a00 = RDA(2 * (p), ck0), a01 = RDA(2 * (p), ck1);                    \
    frag8 a10 = RDA(2 * (p) + 1, ck0), a11 = RDA(2 * (p) + 1, ck1);            \
    SSTAGE;                                                                    \
    SWAIT;                                                                     \
    __builtin_amdgcn_s_barrier();                                              \
    __builtin_amdgcn_s_setprio(1);                                             \
    acc[2*(p)][0]   = MF(a00, b00, acc[2*(p)][0]);                             \
    acc[2*(p)][1]   = MF(a00, b10, acc[2*(p)][1]);                             \
    acc[2*(p)][2]   = MF(a00, b20, acc[2*(p)][2]);                             \
    acc[2*(p)][3]   = MF(a00, b30, acc[2*(p)][3]);                             \
    acc[2*(p)+1][0] = MF(a10, b00, acc[2*(p)+1][0]);                           \
    acc[2*(p)+1][1] = MF(a10, b10, acc[2*(p)+1][1]);                           \
    acc[2*(p)+1][2] = MF(a10, b20, acc[2*(p)+1][2]);                           \
    acc[2*(p)+1][3] = MF(a10, b30, acc[2*(p)+1][3]);                           \
    acc[2*(p)][0]   = MF(a01, b01, acc[2*(p)][0]);                             \
    acc[2*(p)][1]   = MF(a01, b11, acc[2*(p)][1]);                             \
    acc[2*(p)][2]   = MF(a01, b21, acc[2*(p)][2]);                             \
    acc[2*(p)][3]   = MF(a01, b31, acc[2*(p)][3]);                             \
    acc[2*(p)+1][0] = MF(a11, b01, acc[2*(p)+1][0]);                           \
    acc[2*(p)+1][1] = MF(a11, b11, acc[2*(p)+1][1]);                           \
    acc[2*(p)+1][2] = MF(a11, b21, acc[2*(p)+1][2]);                           \
    acc[2*(p)+1][3] = MF(a11, b31, acc[2*(p)+1][3]);                           \
    __builtin_amdgcn_s_setprio(0);                                             \
    __builtin_amdgcn_s_barrier();                                              \
  } while (0)

#define VM4 asm volatile("s_waitcnt vmcnt(4)" ::: "memory")
#define VM0 asm volatile("s_waitcnt vmcnt(0)" ::: "memory")
#define NOW ((void)0)

#define TILE(t, SA, SB, SWAIT) do {                                            \
    const int _bp2 = ((t) & 1) * 2;                                            \
    char* ab = lds + ((_bp2 + wm) << 14);                                      \
    char* bb = lds + 65536 + ((_bp2 + bhalf) << 14);                           \
    PHASE(0, { if (SA) STAGE(0, 0, (t) + 1, ((t) + 1) & 1); }, NOW);           \
    PHASE(1, { if (SA) STAGE(0, 1, (t) + 1, ((t) + 1) & 1); }, NOW);           \
    PHASE(2, { if (SB) STAGE(1, 0, (t) + 2, (t) & 1); }, NOW);                 \
    PHASE(3, { if (SB) STAGE(1, 1, (t) + 2, (t) & 1); }, SWAIT);               \
  } while (0)

template <typename OutT>
__global__ __launch_bounds__(512, 2) void gemm8(const bf16* __restrict__ A,
                                                const bf16* __restrict__ Bt,
                                                OutT* __restrict__ C) {
  __shared__ __align__(16) char lds[131072];
  const int K = 4096, N = 4096;
  const int t = threadIdx.x;
  const int lane = t & 63, w = t >> 6;
  const int wm = w >> 2, wn = w & 3;
  const int lr = lane & 15, lg = lane >> 4;
  const int bhalf = wn >> 1;

  const int bid = blockIdx.x;
  const int wg = (bid & 7) * 32 + (bid >> 3);
  const int m0 = (wg >> 4) * 256, n0 = (wg & 15) * 256;

  const bf16* gA[2][2];
  const bf16* gB[2][2];
  int ldsOff0, ldsOff1;
  {
    int c0 = (w * 2 + 0) * 64 + lane;
    int c1 = (w * 2 + 1) * 64 + lane;
    int r0 = c0 >> 3, r1 = c1 >> 3;
    int e0 = ((c0 & 7) ^ (r0 & 7)) * 8;
    int e1 = ((c1 & 7) ^ (r1 & 7)) * 8;
    ldsOff0 = c0 * 16; ldsOff1 = c1 * 16;
    gA[0][0] = A + (size_t)(m0 + r0) * K + e0;
    gA[0][1] = A + (size_t)(m0 + r1) * K + e1;
    gA[1][0] = A + (size_t)(m0 + 128 + r0) * K + e0;
    gA[1][1] = A + (size_t)(m0 + 128 + r1) * K + e1;
    gB[0][0] = Bt + (size_t)(n0 + r0) * K + e0;
    gB[0][1] = Bt + (size_t)(n0 + r1) * K + e1;
    gB[1][0] = Bt + (size_t)(n0 + 128 + r0) * K + e0;
    gB[1][1] = Bt + (size_t)(n0 + 128 + r1) * K + e1;
  }

  const int swz = (lr & 7) << 4;
  const int ck0 = (lg * 16) ^ swz;
  const int ck1 = (64 + lg * 16) ^ swz;
  const int aRowB = lr * 128;
  const int bRowB = ((wn & 1) * 64 + lr) * 128;

  f32x4 acc[8][4];
#pragma unroll
  for (int mi = 0; mi < 8; ++mi)
#pragma unroll
    for (int ni = 0; ni < 4; ++ni) acc[mi][ni] = (f32x4){0.f, 0.f, 0.f, 0.f};

  frag8 b00, b01, b10, b11, b20, b21, b30, b31;

  STAGE(1, 0, 0, 0); STAGE(1, 1, 0, 0);
  STAGE(0, 0, 0, 0); STAGE(0, 1, 0, 0);
  STAGE(1, 0, 1, 1); STAGE(1, 1, 1, 1);
  VM4;
  __builtin_amdgcn_s_barrier();

  for (int tt = 0; tt < 62; tt += 2) {
    TILE(tt, 1, 1, VM4);
    TILE(tt + 1, 1, 1, VM4);
  }
  TILE(62, 1, 0, VM0);
  TILE(63, 0, 0, NOW);

#pragma unroll
  for (int mi = 0; mi < 8; ++mi)
#pragma unroll
    for (int ni = 0; ni < 4; ++ni) {
      f32x4 v = acc[mi][ni];
      int col = n0 + wn * 64 + ni * 16 + lr;
#pragma unroll
      for (int i = 0; i < 4; ++i) {
        int row = m0 + wm * 128 + mi * 16 + lg * 4 + i;
        storeC(C, (size_t)row * N + col, v[i]);
      }
    }
}

// ---------------- RoPE (in-place on q,k) ----------------
__global__ __launch_bounds__(256) void rope_kernel(bf16* __restrict__ q, bf16* __restrict__ k,
                                                   const float* __restrict__ fc,
                                                   const float* __restrict__ fs) {
  int idx = blockIdx.x * 256 + threadIdx.x;
  int i = idx & 63;
  int s = (idx >> 11) & 1023;
  float c = fc[s * 64 + i], sn = fs[s * 64 + i];
  uint32_t* qp = reinterpret_cast<uint32_t*>(q) + idx;
  uint32_t* kp = reinterpret_cast<uint32_t*>(k) + idx;
  union { uint32_t u; bf16 h[2]; } a, r;
  a.u = *qp;
  {
    float x = __bfloat162float(a.h[0]), y = __bfloat162float(a.h[1]);
    r.h[0] = __float2bfloat16(x * c - y * sn);
    r.h[1] = __float2bfloat16(x * sn + y * c);
    *qp = r.u;
  }
  a.u = *kp;
  {
    float x = __bfloat162float(a.h[0]), y = __bfloat162float(a.h[1]);
    r.h[0] = __float2bfloat16(x * c - y * sn);
    r.h[1] = __float2bfloat16(x * sn + y * c);
    *kp = r.u;
  }
}

// ---------------- V transpose: v[b][s][h][d] -> vt[b][h][d][s] ----------------
__global__ __launch_bounds__(256) void transpose_v_kernel(const bf16* __restrict__ v,
                                                          bf16* __restrict__ vt) {
  __shared__ unsigned short tile[32][40];
  const int st = blockIdx.x * 32;
  const int dt = blockIdx.y * 32;
  const int bh = blockIdx.z;
  const int b = bh >> 5, h = bh & 31;
  const int t = threadIdx.x;
  const int r = t >> 3, c4 = (t & 7) * 4;
  const unsigned short* src = reinterpret_cast<const unsigned short*>(v) +
      ((size_t)(b * 1024 + st + r)) * 4096 + h * 128 + dt + c4;
  uint2 d = *reinterpret_cast<const uint2*>(src);
  tile[r][c4 + 0] = (unsigned short)(d.x & 0xffff);
  tile[r][c4 + 1] = (unsigned short)(d.x >> 16);
  tile[r][c4 + 2] = (unsigned short)(d.y & 0xffff);
  tile[r][c4 + 3] = (unsigned short)(d.y >> 16);
  __syncthreads();
  uint2 o;
  o.x = (uint32_t)tile[c4 + 0][r] | ((uint32_t)tile[c4 + 1][r] << 16);
  o.y = (uint32_t)tile[c4 + 2][r] | ((uint32_t)tile[c4 + 3][r] << 16);
  unsigned short* dst = reinterpret_cast<unsigned short*>(vt) +
      ((size_t)bh * 128 + dt + r) * 1024 + st + c4;
  *reinterpret_cast<uint2*>(dst) = o;
}

// ---------------- Flash attention v2: QBLK=128, 8 waves, double-buffered K/V ----------------
// LDS 80KB: K[2][64x128] @0, V[2][128x64] @32768, P[8][16x64] @65536. All XOR-swizzled
// (byte ^= (row&7)<<4) via pre-swizzled global source (linear gl_lds dest).
// Schedule per kv-tile: vmcnt(4);bar | QK^T | bar | stageK(kt+2) | softmax | PV | bar | stageV(kt+2)
__global__ __launch_bounds__(512, 4) void attn_kernel(const bf16* __restrict__ q,
                                                      const bf16* __restrict__ k,
                                                      const bf16* __restrict__ vt,
                                                      bf16* __restrict__ out) {
  __shared__ __align__(16) char als[81920];
  const int qt = blockIdx.x, h = blockIdx.y, b = blockIdx.z;
  const int t = threadIdx.x;
  const int lane = t & 63, w = t >> 6;
  const int lr = lane & 15, lg = lane >> 4;
  const int NT = 2 * qt + 2;

  // Q fragments (A-operand): row=lane&15, k=(lane>>4)*8+e
  frag8 aq[4];
  {
    const bf16* qp = q + ((size_t)(b * 1024 + qt * 128 + w * 16 + lr)) * 4096 + h * 128 + lg * 8;
#pragma unroll
    for (int ks = 0; ks < 4; ++ks) aq[ks] = *reinterpret_cast<const frag8*>(qp + ks * 32);
  }

  const bf16* kbase = k + (size_t)b * 1024 * 4096 + h * 128;
  const bf16* vbase = vt + ((size_t)(b * 32 + h)) * 128 * 1024;

  // staging addresses: 2 chunks of 16B per thread per 16KB tile
  const int L0 = t * 16, L1 = (t + 512) * 16;
  const int kr0 = L0 >> 8, kr1 = L1 >> 8;
  const size_t kOff0 = (size_t)kr0 * 4096 + (((L0 & 255) ^ ((kr0 & 7) << 4)) >> 1);
  const size_t kOff1 = (size_t)kr1 * 4096 + (((L1 & 255) ^ ((kr1 & 7) << 4)) >> 1);
  const int vr0 = L0 >> 7, vr1 = L1 >> 7;
  const size_t vOff0 = (size_t)vr0 * 1024 + (((L0 & 127) ^ ((vr0 & 7) << 4)) >> 1);
  const size_t vOff1 = (size_t)vr1 * 1024 + (((L1 & 127) ^ ((vr1 & 7) << 4)) >> 1);

#define STAGE_K(tt, bp) do { char* _d = als + (bp) * 16384;                    \
    gl_lds16(kbase + (size_t)(tt) * 262144 + kOff0, _d + L0);                  \
    gl_lds16(kbase + (size_t)(tt) * 262144 + kOff1, _d + L1); } while (0)
#define STAGE_V(tt, bp) do { char* _d = als + 32768 + (bp) * 16384;            \
    gl_lds16(vbase + (size_t)(tt) * 64 + vOff0, _d + L0);                      \
    gl_lds16(vbase + (size_t)(tt) * 64 + vOff1, _d + L1); } while (0)

  f32x4 oacc[8] = {};
  float mrow[4] = {-1e30f, -1e30f, -1e30f, -1e30f};
  float lrow[4] = {0.f, 0.f, 0.f, 0.f};
  char* Pw = als + 65536 + w * 2048;
  const float scale = 0.08838834764831845f;  // 1/sqrt(128)
  const int qmaxw = qt * 128 + w * 16 + 15;  // highest q row this wave owns

  // prologue: K0,V0,K1,V1 (8 loads in flight)
  STAGE_K(0, 0); STAGE_V(0, 0);
  STAGE_K(1, 1); STAGE_V(1, 1);

  for (int kt = 0; kt < NT; ++kt) {
    const int cur = kt & 1;
    const bool act = (kt * 64 <= qmaxw);       // wave has unmasked work this tile
    const bool domask = (kt >= 2 * qt);        // diagonal region
    char* Kc = als + cur * 16384;
    char* Vc = als + 32768 + cur * 16384;

    if (kt + 1 < NT) { VM4; } else { VM0; }
    __builtin_amdgcn_s_barrier();

    // S = Q K^T over HD=128 (4 k-steps)
    f32x4 sacc[4] = {};
    if (act) {
      __builtin_amdgcn_s_setprio(1);
#pragma unroll
      for (int ks = 0; ks < 4; ++ks) {
#pragma unroll
        for (int ni = 0; ni < 4; ++ni) {
          int n = ni * 16 + lr;
          frag8 bk = *reinterpret_cast<const frag8*>(
              Kc + n * 256 + ((ks * 64 + lg * 16) ^ ((n & 7) << 4)));
          sacc[ni] = MF(aq[ks], bk, sacc[ni]);
        }
      }
      __builtin_amdgcn_s_setprio(0);
    }
    __builtin_amdgcn_s_barrier();
    if (kt + 2 < NT) STAGE_K(kt + 2, cur);   // lands under softmax+PV

    if (act) {
      // scale + causal mask (in place)
#pragma unroll
      for (int ni = 0; ni < 4; ++ni)
#pragma unroll
        for (int i = 0; i < 4; ++i) {
          float x = sacc[ni][i] * scale;
          if (domask) {
            int qr = qt * 128 + w * 16 + lg * 4 + i;
            int kc = kt * 64 + ni * 16 + lr;
            if (kc > qr) x = -1e30f;
          }
          sacc[ni][i] = x;
        }

      // online softmax (rows across 16 lr lanes)
      float fs_[4];
#pragma unroll
      for (int i = 0; i < 4; ++i) {
        float pm = fmaxf(fmaxf(sacc[0][i], sacc[1][i]), fmaxf(sacc[2][i], sacc[3][i]));
#pragma unroll
        for (int m = 1; m <= 8; m <<= 1) pm = fmaxf(pm, __shfl_xor(pm, m));
        float mn = fmaxf(mrow[i], pm);
        float f = __expf(mrow[i] - mn);
        float rs = 0.f;
#pragma unroll
        for (int ni = 0; ni < 4; ++ni) {
          float p = __expf(sacc[ni][i] - mn);
          sacc[ni][i] = p;
          rs += p;
        }
#pragma unroll
        for (int m = 1; m <= 8; m <<= 1) rs += __shfl_xor(rs, m);
        lrow[i] = lrow[i] * f + rs;
        mrow[i] = mn;
        fs_[i] = f;
      }
#pragma unroll
      for (int nj = 0; nj < 8; ++nj)
#pragma unroll
        for (int i = 0; i < 4; ++i) oacc[nj][i] *= fs_[i];

      // P -> LDS (bf16, swizzled, wave-private strip)
#pragma unroll
      for (int ni = 0; ni < 4; ++ni)
#pragma unroll
        for (int i = 0; i < 4; ++i) {
          int prow = lg * 4 + i;
          int pb = prow * 128 + (((ni * 16 + lr) * 2) ^ ((prow & 7) << 4));
          *reinterpret_cast<bf16*>(Pw + pb) = __float2bfloat16(sacc[ni][i]);
        }

      // O += P V (2 k-steps of 32)
      __builtin_amdgcn_s_setprio(1);
#pragma unroll
      for (int ks2 = 0; ks2 < 2; ++ks2) {
        frag8 ap = *reinterpret_cast<const frag8*>(
            Pw + lr * 128 + ((ks2 * 64 + lg * 16) ^ ((lr & 7) << 4)));
#pragma unroll
        for (int nj = 0; nj < 8; ++nj) {
          int d = nj * 16 + lr;
          frag8 bv = *reinterpret_cast<const frag8*>(
              Vc + d * 128 + ((ks2 * 64 + lg * 16) ^ ((d & 7) << 4)));
          oacc[nj] = MF(ap, bv, oacc[nj]);
        }
      }
      __builtin_amdgcn_s_setprio(0);
    }
    __builtin_amdgcn_s_barrier();
    if (kt + 2 < NT) STAGE_V(kt + 2, cur);   // lands before vmcnt(4) two tiles later
  }

  // normalize + write (b,s,h,d) bf16
#pragma unroll
  for (int nj = 0; nj < 8; ++nj)
#pragma unroll
    for (int i = 0; i < 4; ++i) {
      int srow = qt * 128 + w * 16 + lg * 4 + i;
      out[((size_t)(b * 1024 + srow)) * 4096 + h * 128 + nj * 16 + lr] =
          __float2bfloat16(oacc[nj][i] / lrow[i]);
    }
#undef STAGE_K
#undef STAGE_V
}

// ---------------- host launch ----------------
extern "C" void kernel_launch(void* const* d_in, const int* in_sizes, int n_in,
                              void* d_out, int out_size, void* d_ws, size_t ws_size,
                              hipStream_t stream) {
  const float* x  = (const float*)d_in[0];
  const float* fc = (const float*)d_in[2];
  const float* fs = (const float*)d_in[3];
  const float* wq = (const float*)d_in[5];
  const float* wk = (const float*)d_in[6];
  const float* wv = (const float*)d_in[7];
  const float* wo = (const float*)d_in[8];
  float* out = (float*)d_out;

  const size_t SZ = (size_t)4096 * 4096 * 2;
  char* w = (char*)d_ws;
  bf16* xb = (bf16*)(w);
  bf16* wb = (bf16*)(w + SZ);
  bf16* qb = (bf16*)(w + 2 * SZ);
  bf16* kb = (bf16*)(w + 3 * SZ);
  bf16* vb = (bf16*)(w + 4 * SZ);
  bf16* vtb = xb;  // xb dead after QKV GEMMs
  bf16* ao  = vb;  // vb dead after transpose

  const int n8 = 4096 * 4096 / 8;
  dim3 cgrd(n8 / 256), blk(256);
  dim3 ggrd(256);
  dim3 gblk(512);

  conv_kernel<<<cgrd, blk, 0, stream>>>(x, xb, n8);
  conv_kernel<<<cgrd, blk, 0, stream>>>(wq, wb, n8);
  gemm8<bf16><<<ggrd, gblk, 0, stream>>>(xb, wb, qb);
  conv_kernel<<<cgrd, blk, 0, stream>>>(wk, wb, n8);
  gemm8<bf16><<<ggrd, gblk, 0, stream>>>(xb, wb, kb);
  conv_kernel<<<cgrd, blk, 0, stream>>>(wv, wb, n8);
  gemm8<bf16><<<ggrd, gblk, 0, stream>>>(xb, wb, vb);
  rope_kernel<<<dim3(32768), blk, 0, stream>>>(qb, kb, fc, fs);
  transpose_v_kernel<<<dim3(32, 4, 128), blk, 0, stream>>>(vb, vtb);
  attn_kernel<<<dim3(8, 32, 4), gblk, 0, stream>>>(qb, kb, vtb, ao);
  conv_kernel<<<cgrd, blk, 0, stream>>>(wo, wb, n8);
  gemm8<float><<<ggrd, gblk, 0, stream>>>(ao, wb, out);
}

// Round 4
// 686.077 us; speedup vs baseline: 1.5140x; 1.0383x over previous
//
#include <hip/hip_runtime.h>
#include <hip/hip_bf16.h>
#include <cstdint>

typedef __hip_bfloat16 bf16;
typedef __attribute__((ext_vector_type(8))) short frag8;   // 8 bf16 (4 VGPRs) MFMA operand
typedef __attribute__((ext_vector_type(4))) float f32x4;   // MFMA accumulator

#define DEV __device__ __forceinline__

DEV void gl_lds16(const void* g, void* l) {
  __builtin_amdgcn_global_load_lds(
      (const __attribute__((address_space(1))) void*)g,
      (__attribute__((address_space(3))) void*)l, 16, 0, 0);
}

DEV void storeC(float* C, size_t idx, float v) { C[idx] = v; }
DEV void storeC(bf16* C, size_t idx, float v) { C[idx] = __float2bfloat16(v); }

// ---------------- f32 -> bf16 conversion, 8 elems/thread ----------------
__global__ __launch_bounds__(256) void conv_kernel(const float* __restrict__ in,
                                                   bf16* __restrict__ out, int n8) {
  int i = blockIdx.x * 256 + threadIdx.x;
  if (i >= n8) return;
  const float4* in4 = reinterpret_cast<const float4*>(in);
  float4 a = in4[2 * i], b = in4[2 * i + 1];
  union { frag8 v; bf16 h[8]; } u;
  u.h[0] = __float2bfloat16(a.x); u.h[1] = __float2bfloat16(a.y);
  u.h[2] = __float2bfloat16(a.z); u.h[3] = __float2bfloat16(a.w);
  u.h[4] = __float2bfloat16(b.x); u.h[5] = __float2bfloat16(b.y);
  u.h[6] = __float2bfloat16(b.z); u.h[7] = __float2bfloat16(b.w);
  *reinterpret_cast<frag8*>(out + (size_t)i * 8) = u.v;
}

// ---------------- GEMM (8-phase 256^2, BK=64, 8 waves): C = A * Bt^T ----------------
#define MF(a, b, c) __builtin_amdgcn_mfma_f32_16x16x32_bf16(a, b, c, 0, 0, 0)

#define STAGE(isB, h, tt, bp) do {                                             \
    char* _d = lds + ((isB) * 65536) + ((((bp) * 2) + (h)) << 14);             \
    gl_lds16(((isB) ? gB : gA)[h][0] + (size_t)(tt) * 64, _d + ldsOff0);       \
    gl_lds16(((isB) ? gB : gA)[h][1] + (size_t)(tt) * 64, _d + ldsOff1);       \
  } while (0)

#define RDA(mi, ckk) (*(const frag8*)(ab + aRowB + (mi) * 2048 + (ckk)))
#define RDB(ni, ckk) (*(const frag8*)(bb + bRowB + (ni) * 2048 + (ckk)))

#define PHASE(p, SSTAGE, SWAIT) do {                                           \
    if ((p) == 0) {                                                            \
      b00 = RDB(0, ck0); b01 = RDB(0, ck1); b10 = RDB(1, ck0); b11 = RDB(1, ck1); \
      b20 = RDB(2, ck0); b21 = RDB(2, ck1); b30 = RDB(3, ck0); b31 = RDB(3, ck1); \
    }                                                                          \
    frag8 a00 = RDA(2 * (p), ck0), a01 = RDA(2 * (p), ck1);                    \
    frag8 a10 = RDA(2 * (p) + 1, ck0), a11 = RDA(2 * (p) + 1, ck1);            \
    SSTAGE;                                                                    \
    SWAIT;                                                                     \
    __builtin_amdgcn_s_barrier();                                              \
    __builtin_amdgcn_s_setprio(1);                                             \
    acc[2*(p)][0]   = MF(a00, b00, acc[2*(p)][0]);                             \
    acc[2*(p)][1]   = MF(a00, b10, acc[2*(p)][1]);                             \
    acc[2*(p)][2]   = MF(a00, b20, acc[2*(p)][2]);                             \
    acc[2*(p)][3]   = MF(a00, b30, acc[2*(p)][3]);                             \
    acc[2*(p)+1][0] = MF(a10, b00, acc[2*(p)+1][0]);                           \
    acc[2*(p)+1][1] = MF(a10, b10, acc[2*(p)+1][1]);                           \
    acc[2*(p)+1][2] = MF(a10, b20, acc[2*(p)+1][2]);                           \
    acc[2*(p)+1][3] = MF(a10, b30, acc[2*(p)+1][3]);                           \
    acc[2*(p)][0]   = MF(a01, b01, acc[2*(p)][0]);                             \
    acc[2*(p)][1]   = MF(a01, b11, acc[2*(p)][1]);                             \
    acc[2*(p)][2]   = MF(a01, b21, acc[2*(p)][2]);                             \
    acc[2*(p)][3]   = MF(a01, b31, acc[2*(p)][3]);                             \
    acc[2*(p)+1][0] = MF(a11, b01, acc[2*(p)+1][0]);                           \
    acc[2*(p)+1][1] = MF(a11, b11, acc[2*(p)+1][1]);                           \
    acc[2*(p)+1][2] = MF(a11, b21, acc[2*(p)+1][2]);                           \
    acc[2*(p)+1][3] = MF(a11, b31, acc[2*(p)+1][3]);                           \
    __builtin_amdgcn_s_setprio(0);                                             \
    __builtin_amdgcn_s_barrier();                                              \
  } while (0)

#define VM4 asm volatile("s_waitcnt vmcnt(4)" ::: "memory")
#define VM0 asm volatile("s_waitcnt vmcnt(0)" ::: "memory")
#define NOW ((void)0)

#define TILE(t, SA, SB, SWAIT) do {                                            \
    const int _bp2 = ((t) & 1) * 2;                                            \
    char* ab = lds + ((_bp2 + wm) << 14);                                      \
    char* bb = lds + 65536 + ((_bp2 + bhalf) << 14);                           \
    PHASE(0, { if (SA) STAGE(0, 0, (t) + 1, ((t) + 1) & 1); }, NOW);           \
    PHASE(1, { if (SA) STAGE(0, 1, (t) + 1, ((t) + 1) & 1); }, NOW);           \
    PHASE(2, { if (SB) STAGE(1, 0, (t) + 2, (t) & 1); }, NOW);                 \
    PHASE(3, { if (SB) STAGE(1, 1, (t) + 2, (t) & 1); }, SWAIT);               \
  } while (0)

template <typename OutT>
__global__ __launch_bounds__(512, 2) void gemm8(const bf16* __restrict__ A,
                                                const bf16* __restrict__ Bt,
                                                OutT* __restrict__ C) {
  __shared__ __align__(16) char lds[131072];
  const int K = 4096, N = 4096;
  const int t = threadIdx.x;
  const int lane = t & 63, w = t >> 6;
  const int wm = w >> 2, wn = w & 3;
  const int lr = lane & 15, lg = lane >> 4;
  const int bhalf = wn >> 1;

  const int bid = blockIdx.x;
  const int wg = (bid & 7) * 32 + (bid >> 3);
  const int m0 = (wg >> 4) * 256, n0 = (wg & 15) * 256;

  const bf16* gA[2][2];
  const bf16* gB[2][2];
  int ldsOff0, ldsOff1;
  {
    int c0 = (w * 2 + 0) * 64 + lane;
    int c1 = (w * 2 + 1) * 64 + lane;
    int r0 = c0 >> 3, r1 = c1 >> 3;
    int e0 = ((c0 & 7) ^ (r0 & 7)) * 8;
    int e1 = ((c1 & 7) ^ (r1 & 7)) * 8;
    ldsOff0 = c0 * 16; ldsOff1 = c1 * 16;
    gA[0][0] = A + (size_t)(m0 + r0) * K + e0;
    gA[0][1] = A + (size_t)(m0 + r1) * K + e1;
    gA[1][0] = A + (size_t)(m0 + 128 + r0) * K + e0;
    gA[1][1] = A + (size_t)(m0 + 128 + r1) * K + e1;
    gB[0][0] = Bt + (size_t)(n0 + r0) * K + e0;
    gB[0][1] = Bt + (size_t)(n0 + r1) * K + e1;
    gB[1][0] = Bt + (size_t)(n0 + 128 + r0) * K + e0;
    gB[1][1] = Bt + (size_t)(n0 + 128 + r1) * K + e1;
  }

  const int swz = (lr & 7) << 4;
  const int ck0 = (lg * 16) ^ swz;
  const int ck1 = (64 + lg * 16) ^ swz;
  const int aRowB = lr * 128;
  const int bRowB = ((wn & 1) * 64 + lr) * 128;

  f32x4 acc[8][4];
#pragma unroll
  for (int mi = 0; mi < 8; ++mi)
#pragma unroll
    for (int ni = 0; ni < 4; ++ni) acc[mi][ni] = (f32x4){0.f, 0.f, 0.f, 0.f};

  frag8 b00, b01, b10, b11, b20, b21, b30, b31;

  STAGE(1, 0, 0, 0); STAGE(1, 1, 0, 0);
  STAGE(0, 0, 0, 0); STAGE(0, 1, 0, 0);
  STAGE(1, 0, 1, 1); STAGE(1, 1, 1, 1);
  VM4;
  __builtin_amdgcn_s_barrier();

  for (int tt = 0; tt < 62; tt += 2) {
    TILE(tt, 1, 1, VM4);
    TILE(tt + 1, 1, 1, VM4);
  }
  TILE(62, 1, 0, VM0);
  TILE(63, 0, 0, NOW);

#pragma unroll
  for (int mi = 0; mi < 8; ++mi)
#pragma unroll
    for (int ni = 0; ni < 4; ++ni) {
      f32x4 v = acc[mi][ni];
      int col = n0 + wn * 64 + ni * 16 + lr;
#pragma unroll
      for (int i = 0; i < 4; ++i) {
        int row = m0 + wm * 128 + mi * 16 + lg * 4 + i;
        storeC(C, (size_t)row * N + col, v[i]);
      }
    }
}

// ---------------- RoPE (in-place on q,k) ----------------
__global__ __launch_bounds__(256) void rope_kernel(bf16* __restrict__ q, bf16* __restrict__ k,
                                                   const float* __restrict__ fc,
                                                   const float* __restrict__ fs) {
  int idx = blockIdx.x * 256 + threadIdx.x;
  int i = idx & 63;
  int s = (idx >> 11) & 1023;
  float c = fc[s * 64 + i], sn = fs[s * 64 + i];
  uint32_t* qp = reinterpret_cast<uint32_t*>(q) + idx;
  uint32_t* kp = reinterpret_cast<uint32_t*>(k) + idx;
  union { uint32_t u; bf16 h[2]; } a, r;
  a.u = *qp;
  {
    float x = __bfloat162float(a.h[0]), y = __bfloat162float(a.h[1]);
    r.h[0] = __float2bfloat16(x * c - y * sn);
    r.h[1] = __float2bfloat16(x * sn + y * c);
    *qp = r.u;
  }
  a.u = *kp;
  {
    float x = __bfloat162float(a.h[0]), y = __bfloat162float(a.h[1]);
    r.h[0] = __float2bfloat16(x * c - y * sn);
    r.h[1] = __float2bfloat16(x * sn + y * c);
    *kp = r.u;
  }
}

// ---------------- V transpose: v[b][s][h][d] -> vt[b][h][d][s] ----------------
__global__ __launch_bounds__(256) void transpose_v_kernel(const bf16* __restrict__ v,
                                                          bf16* __restrict__ vt) {
  __shared__ unsigned short tile[32][40];
  const int st = blockIdx.x * 32;
  const int dt = blockIdx.y * 32;
  const int bh = blockIdx.z;
  const int b = bh >> 5, h = bh & 31;
  const int t = threadIdx.x;
  const int r = t >> 3, c4 = (t & 7) * 4;
  const unsigned short* src = reinterpret_cast<const unsigned short*>(v) +
      ((size_t)(b * 1024 + st + r)) * 4096 + h * 128 + dt + c4;
  uint2 d = *reinterpret_cast<const uint2*>(src);
  tile[r][c4 + 0] = (unsigned short)(d.x & 0xffff);
  tile[r][c4 + 1] = (unsigned short)(d.x >> 16);
  tile[r][c4 + 2] = (unsigned short)(d.y & 0xffff);
  tile[r][c4 + 3] = (unsigned short)(d.y >> 16);
  __syncthreads();
  uint2 o;
  o.x = (uint32_t)tile[c4 + 0][r] | ((uint32_t)tile[c4 + 1][r] << 16);
  o.y = (uint32_t)tile[c4 + 2][r] | ((uint32_t)tile[c4 + 3][r] << 16);
  unsigned short* dst = reinterpret_cast<unsigned short*>(vt) +
      ((size_t)bh * 128 + dt + r) * 1024 + st + c4;
  *reinterpret_cast<uint2*>(dst) = o;
}

// ---------------- Flash attention v3: swapped QK^T (lane owns one q-row) ----------------
// QBLK=128, 8 waves, double-buffered K/V in LDS (80KB), XOR-swizzled.
// QK^T computed as mfma(K_frag, Q_frag) -> S^T: lane (lr,lg) holds S[kc=ni*16+lg*4+i][qrow=lr].
// Row softmax: in-register 16-value reduce + shfl_xor(16,32); f redistributed to oacc row
// owners (row=lg*4+i) via 4 __shfl.
__global__ __launch_bounds__(512, 4) void attn_kernel(const bf16* __restrict__ q,
                                                      const bf16* __restrict__ k,
                                                      const bf16* __restrict__ vt,
                                                      bf16* __restrict__ out) {
  __shared__ __align__(16) char als[81920];
  const int qt = blockIdx.x, h = blockIdx.y, b = blockIdx.z;
  const int t = threadIdx.x;
  const int lane = t & 63, w = t >> 6;
  const int lr = lane & 15, lg = lane >> 4;
  const int NT = 2 * qt + 2;

  // Q fragments: lane holds Q[qrow=lr][d=ks*32+lg*8+e] — valid as A (row=lr) or B (col=lr)
  frag8 aq[4];
  {
    const bf16* qp = q + ((size_t)(b * 1024 + qt * 128 + w * 16 + lr)) * 4096 + h * 128 + lg * 8;
#pragma unroll
    for (int ks = 0; ks < 4; ++ks) aq[ks] = *reinterpret_cast<const frag8*>(qp + ks * 32);
  }

  const bf16* kbase = k + (size_t)b * 1024 * 4096 + h * 128;
  const bf16* vbase = vt + ((size_t)(b * 32 + h)) * 128 * 1024;

  const int L0 = t * 16, L1 = (t + 512) * 16;
  const int kr0 = L0 >> 8, kr1 = L1 >> 8;
  const size_t kOff0 = (size_t)kr0 * 4096 + (((L0 & 255) ^ ((kr0 & 7) << 4)) >> 1);
  const size_t kOff1 = (size_t)kr1 * 4096 + (((L1 & 255) ^ ((kr1 & 7) << 4)) >> 1);
  const int vr0 = L0 >> 7, vr1 = L1 >> 7;
  const size_t vOff0 = (size_t)vr0 * 1024 + (((L0 & 127) ^ ((vr0 & 7) << 4)) >> 1);
  const size_t vOff1 = (size_t)vr1 * 1024 + (((L1 & 127) ^ ((vr1 & 7) << 4)) >> 1);

#define STAGE_K(tt, bp) do { char* _d = als + (bp) * 16384;                    \
    gl_lds16(kbase + (size_t)(tt) * 262144 + kOff0, _d + L0);                  \
    gl_lds16(kbase + (size_t)(tt) * 262144 + kOff1, _d + L1); } while (0)
#define STAGE_V(tt, bp) do { char* _d = als + 32768 + (bp) * 16384;            \
    gl_lds16(vbase + (size_t)(tt) * 64 + vOff0, _d + L0);                      \
    gl_lds16(vbase + (size_t)(tt) * 64 + vOff1, _d + L1); } while (0)

  f32x4 oacc[8] = {};
  float mrow = -1e30f, lrow = 0.f;   // scalar: lane owns q-row (w*16 + lr)
  char* Pw = als + 65536 + w * 2048;
  const float scale = 0.08838834764831845f;  // 1/sqrt(128)
  const int qmaxw = qt * 128 + w * 16 + 15;
  const int qr_g = qt * 128 + w * 16 + lr;   // this lane's q-row (global)

  STAGE_K(0, 0); STAGE_V(0, 0);
  STAGE_K(1, 1); STAGE_V(1, 1);

  for (int kt = 0; kt < NT; ++kt) {
    const int cur = kt & 1;
    const bool act = (kt * 64 <= qmaxw);
    const bool domask = (kt >= 2 * qt);
    char* Kc = als + cur * 16384;
    char* Vc = als + 32768 + cur * 16384;

    if (kt + 1 < NT) { VM4; } else { VM0; }
    __builtin_amdgcn_s_barrier();

    // S^T = K Q^T over HD=128 (4 k-steps): sacc[ni][i] = S[kc=ni*16+lg*4+i][qrow=lr]
    f32x4 sacc[4] = {};
    if (act) {
      __builtin_amdgcn_s_setprio(1);
#pragma unroll
      for (int ks = 0; ks < 4; ++ks) {
#pragma unroll
        for (int ni = 0; ni < 4; ++ni) {
          int n = ni * 16 + lr;
          frag8 bk = *reinterpret_cast<const frag8*>(
              Kc + n * 256 + ((ks * 64 + lg * 16) ^ ((n & 7) << 4)));
          sacc[ni] = MF(bk, aq[ks], sacc[ni]);   // SWAPPED: A=K, B=Q -> S^T
        }
      }
      __builtin_amdgcn_s_setprio(0);
    }
    __builtin_amdgcn_s_barrier();
    if (kt + 2 < NT) STAGE_K(kt + 2, cur);

    if (act) {
      // scale + causal mask: lane's column is its own q-row
#pragma unroll
      for (int ni = 0; ni < 4; ++ni)
#pragma unroll
        for (int i = 0; i < 4; ++i) {
          float x = sacc[ni][i] * scale;
          if (domask) {
            int kc = kt * 64 + ni * 16 + lg * 4 + i;
            if (kc > qr_g) x = -1e30f;
          }
          sacc[ni][i] = x;
        }

      // softmax for this lane's row: in-register 16-reduce + 2 shfl (lanes lr,lr+16,lr+32,lr+48)
      float pm = sacc[0][0];
#pragma unroll
      for (int ni = 0; ni < 4; ++ni)
#pragma unroll
        for (int i = 0; i < 4; ++i) pm = fmaxf(pm, sacc[ni][i]);
      pm = fmaxf(pm, __shfl_xor(pm, 16));
      pm = fmaxf(pm, __shfl_xor(pm, 32));
      float mn = fmaxf(mrow, pm);
      float f = __expf(mrow - mn);
      float rs = 0.f;
#pragma unroll
      for (int ni = 0; ni < 4; ++ni)
#pragma unroll
        for (int i = 0; i < 4; ++i) {
          float p = __expf(sacc[ni][i] - mn);
          sacc[ni][i] = p;
          rs += p;
        }
      rs += __shfl_xor(rs, 16);
      rs += __shfl_xor(rs, 32);
      lrow = lrow * f + rs;
      mrow = mn;

      // P -> LDS (packed b32 writes, swizzled): P[qrow=lr][kc=ni*16+lg*4+ (0..3)]
#pragma unroll
      for (int ni = 0; ni < 4; ++ni)
#pragma unroll
        for (int j = 0; j < 2; ++j) {
          union { uint32_t u; bf16 hh[2]; } pk;
          pk.hh[0] = __float2bfloat16(sacc[ni][2 * j]);
          pk.hh[1] = __float2bfloat16(sacc[ni][2 * j + 1]);
          int kc2 = (ni * 16 + lg * 4 + 2 * j) * 2;
          *reinterpret_cast<uint32_t*>(Pw + lr * 128 + (kc2 ^ ((lr & 7) << 4))) = pk.u;
        }

      // rescale O: oacc row index is lg*4+i; f is uniform over lg, keyed by lr -> shfl from lane (row)
      float fi0 = __shfl(f, lg * 4 + 0);
      float fi1 = __shfl(f, lg * 4 + 1);
      float fi2 = __shfl(f, lg * 4 + 2);
      float fi3 = __shfl(f, lg * 4 + 3);
#pragma unroll
      for (int nj = 0; nj < 8; ++nj) {
        oacc[nj][0] *= fi0; oacc[nj][1] *= fi1;
        oacc[nj][2] *= fi2; oacc[nj][3] *= fi3;
      }

      // O += P V (2 k-steps of 32)
      __builtin_amdgcn_s_setprio(1);
#pragma unroll
      for (int ks2 = 0; ks2 < 2; ++ks2) {
        frag8 ap = *reinterpret_cast<const frag8*>(
            Pw + lr * 128 + ((ks2 * 64 + lg * 16) ^ ((lr & 7) << 4)));
#pragma unroll
        for (int nj = 0; nj < 8; ++nj) {
          int d = nj * 16 + lr;
          frag8 bv = *reinterpret_cast<const frag8*>(
              Vc + d * 128 + ((ks2 * 64 + lg * 16) ^ ((d & 7) << 4)));
          oacc[nj] = MF(ap, bv, oacc[nj]);
        }
      }
      __builtin_amdgcn_s_setprio(0);
    }
    __builtin_amdgcn_s_barrier();
    if (kt + 2 < NT) STAGE_V(kt + 2, cur);
  }

  // normalize + write: need lrow of row lg*4+i (owned by lane lr = that row)
  float lv0 = __shfl(lrow, lg * 4 + 0);
  float lv1 = __shfl(lrow, lg * 4 + 1);
  float lv2 = __shfl(lrow, lg * 4 + 2);
  float lv3 = __shfl(lrow, lg * 4 + 3);
#pragma unroll
  for (int nj = 0; nj < 8; ++nj) {
    int srow0 = qt * 128 + w * 16 + lg * 4;
    size_t base = ((size_t)(b * 1024 + srow0)) * 4096 + h * 128 + nj * 16 + lr;
    out[base]          = __float2bfloat16(oacc[nj][0] / lv0);
    out[base + 4096]   = __float2bfloat16(oacc[nj][1] / lv1);
    out[base + 8192]   = __float2bfloat16(oacc[nj][2] / lv2);
    out[base + 12288]  = __float2bfloat16(oacc[nj][3] / lv3);
  }
#undef STAGE_K
#undef STAGE_V
}

// ---------------- host launch ----------------
extern "C" void kernel_launch(void* const* d_in, const int* in_sizes, int n_in,
                              void* d_out, int out_size, void* d_ws, size_t ws_size,
                              hipStream_t stream) {
  const float* x  = (const float*)d_in[0];
  const float* fc = (const float*)d_in[2];
  const float* fs = (const float*)d_in[3];
  const float* wq = (const float*)d_in[5];
  const float* wk = (const float*)d_in[6];
  const float* wv = (const float*)d_in[7];
  const float* wo = (const float*)d_in[8];
  float* out = (float*)d_out;

  const size_t SZ = (size_t)4096 * 4096 * 2;
  char* w = (char*)d_ws;
  bf16* xb = (bf16*)(w);
  bf16* wb = (bf16*)(w + SZ);
  bf16* qb = (bf16*)(w + 2 * SZ);
  bf16* kb = (bf16*)(w + 3 * SZ);
  bf16* vb = (bf16*)(w + 4 * SZ);
  bf16* vtb = xb;  // xb dead after QKV GEMMs
  bf16* ao  = vb;  // vb dead after transpose

  const int n8 = 4096 * 4096 / 8;
  dim3 cgrd(n8 / 256), blk(256);
  dim3 ggrd(256);
  dim3 gblk(512);

  conv_kernel<<<cgrd, blk, 0, stream>>>(x, xb, n8);
  conv_kernel<<<cgrd, blk, 0, stream>>>(wq, wb, n8);
  gemm8<bf16><<<ggrd, gblk, 0, stream>>>(xb, wb, qb);
  conv_kernel<<<cgrd, blk, 0, stream>>>(wk, wb, n8);
  gemm8<bf16><<<ggrd, gblk, 0, stream>>>(xb, wb, kb);
  conv_kernel<<<cgrd, blk, 0, stream>>>(wv, wb, n8);
  gemm8<bf16><<<ggrd, gblk, 0, stream>>>(xb, wb, vb);
  rope_kernel<<<dim3(32768), blk, 0, stream>>>(qb, kb, fc, fs);
  transpose_v_kernel<<<dim3(32, 4, 128), blk, 0, stream>>>(vb, vtb);
  attn_kernel<<<dim3(8, 32, 4), gblk, 0, stream>>>(qb, kb, vtb, ao);
  conv_kernel<<<cgrd, blk, 0, stream>>>(wo, wb, n8);
  gemm8<float><<<ggrd, gblk, 0, stream>>>(ao, wb, out);
}

// Round 6
// 677.271 us; speedup vs baseline: 1.5336x; 1.0130x over previous
//
#include <hip/hip_runtime.h>
#include <hip/hip_bf16.h>
#include <cstdint>

typedef __hip_bfloat16 bf16;
typedef __attribute__((ext_vector_type(8))) short frag8;   // 8 bf16 (4 VGPRs) MFMA operand
typedef __attribute__((ext_vector_type(4))) float f32x4;   // MFMA accumulator

#define DEV __device__ __forceinline__

DEV void gl_lds16(const void* g, void* l) {
  __builtin_amdgcn_global_load_lds(
      (const __attribute__((address_space(1))) void*)g,
      (__attribute__((address_space(3))) void*)l, 16, 0, 0);
}

DEV void storeC(float* C, size_t idx, float v) { C[idx] = v; }
DEV void storeC(bf16* C, size_t idx, float v) { C[idx] = __float2bfloat16(v); }

// ---------------- f32 -> bf16 conversion, 8 elems/thread ----------------
__global__ __launch_bounds__(256) void conv_kernel(const float* __restrict__ in,
                                                   bf16* __restrict__ out, int n8) {
  int i = blockIdx.x * 256 + threadIdx.x;
  if (i >= n8) return;
  const float4* in4 = reinterpret_cast<const float4*>(in);
  float4 a = in4[2 * i], b = in4[2 * i + 1];
  union { frag8 v; bf16 h[8]; } u;
  u.h[0] = __float2bfloat16(a.x); u.h[1] = __float2bfloat16(a.y);
  u.h[2] = __float2bfloat16(a.z); u.h[3] = __float2bfloat16(a.w);
  u.h[4] = __float2bfloat16(b.x); u.h[5] = __float2bfloat16(b.y);
  u.h[6] = __float2bfloat16(b.z); u.h[7] = __float2bfloat16(b.w);
  *reinterpret_cast<frag8*>(out + (size_t)i * 8) = u.v;
}

// ---------------- GEMM (8-phase 256^2, BK=64, 8 waves): C = A * Bt^T ----------------
// Optional fused RoPE epilogue (ROPE=true): out row = (b,s) flat, col = h*128+d.
#define MF(a, b, c) __builtin_amdgcn_mfma_f32_16x16x32_bf16(a, b, c, 0, 0, 0)

#define STAGE(isB, h, tt, bp) do {                                             \
    char* _d = lds + ((isB) * 65536) + ((((bp) * 2) + (h)) << 14);             \
    gl_lds16(((isB) ? gB : gA)[h][0] + (size_t)(tt) * 64, _d + ldsOff0);       \
    gl_lds16(((isB) ? gB : gA)[h][1] + (size_t)(tt) * 64, _d + ldsOff1);       \
  } while (0)

#define RDA(mi, ckk) (*(const frag8*)(ab + aRowB + (mi) * 2048 + (ckk)))
#define RDB(ni, ckk) (*(const frag8*)(bb + bRowB + (ni) * 2048 + (ckk)))

#define PHASE(p, SSTAGE, SWAIT) do {                                           \
    if ((p) == 0) {                                                            \
      b00 = RDB(0, ck0); b01 = RDB(0, ck1); b10 = RDB(1, ck0); b11 = RDB(1, ck1); \
      b20 = RDB(2, ck0); b21 = RDB(2, ck1); b30 = RDB(3, ck0); b31 = RDB(3, ck1); \
    }                                                                          \
    frag8 a00 = RDA(2 * (p), ck0), a01 = RDA(2 * (p), ck1);                    \
    frag8 a10 = RDA(2 * (p) + 1, ck0), a11 = RDA(2 * (p) + 1, ck1);            \
    SSTAGE;                                                                    \
    SWAIT;                                                                     \
    __builtin_amdgcn_s_barrier();                                              \
    __builtin_amdgcn_s_setprio(1);                                             \
    acc[2*(p)][0]   = MF(a00, b00, acc[2*(p)][0]);                             \
    acc[2*(p)][1]   = MF(a00, b10, acc[2*(p)][1]);                             \
    acc[2*(p)][2]   = MF(a00, b20, acc[2*(p)][2]);                             \
    acc[2*(p)][3]   = MF(a00, b30, acc[2*(p)][3]);                             \
    acc[2*(p)+1][0] = MF(a10, b00, acc[2*(p)+1][0]);                           \
    acc[2*(p)+1][1] = MF(a10, b10, acc[2*(p)+1][1]);                           \
    acc[2*(p)+1][2] = MF(a10, b20, acc[2*(p)+1][2]);                           \
    acc[2*(p)+1][3] = MF(a10, b30, acc[2*(p)+1][3]);                           \
    acc[2*(p)][0]   = MF(a01, b01, acc[2*(p)][0]);                             \
    acc[2*(p)][1]   = MF(a01, b11, acc[2*(p)][1]);                             \
    acc[2*(p)][2]   = MF(a01, b21, acc[2*(p)][2]);                             \
    acc[2*(p)][3]   = MF(a01, b31, acc[2*(p)][3]);                             \
    acc[2*(p)+1][0] = MF(a11, b01, acc[2*(p)+1][0]);                           \
    acc[2*(p)+1][1] = MF(a11, b11, acc[2*(p)+1][1]);                           \
    acc[2*(p)+1][2] = MF(a11, b21, acc[2*(p)+1][2]);                           \
    acc[2*(p)+1][3] = MF(a11, b31, acc[2*(p)+1][3]);                           \
    __builtin_amdgcn_s_setprio(0);                                             \
    __builtin_amdgcn_s_barrier();                                              \
  } while (0)

#define VM4 asm volatile("s_waitcnt vmcnt(4)" ::: "memory")
#define VM0 asm volatile("s_waitcnt vmcnt(0)" ::: "memory")
#define NOW ((void)0)

#define TILE(t, SA, SB, SWAIT) do {                                            \
    const int _bp2 = ((t) & 1) * 2;                                            \
    char* ab = lds + ((_bp2 + wm) << 14);                                      \
    char* bb = lds + 65536 + ((_bp2 + bhalf) << 14);                           \
    PHASE(0, { if (SA) STAGE(0, 0, (t) + 1, ((t) + 1) & 1); }, NOW);           \
    PHASE(1, { if (SA) STAGE(0, 1, (t) + 1, ((t) + 1) & 1); }, NOW);           \
    PHASE(2, { if (SB) STAGE(1, 0, (t) + 2, (t) & 1); }, NOW);                 \
    PHASE(3, { if (SB) STAGE(1, 1, (t) + 2, (t) & 1); }, SWAIT);               \
  } while (0)

template <typename OutT, bool ROPE>
__global__ __launch_bounds__(512, 2) void gemm8(const bf16* __restrict__ A,
                                                const bf16* __restrict__ Bt,
                                                OutT* __restrict__ C,
                                                const float* __restrict__ fc,
                                                const float* __restrict__ fs) {
  __shared__ __align__(16) char lds[131072];
  const int K = 4096, N = 4096;
  const int t = threadIdx.x;
  const int lane = t & 63, w = t >> 6;
  const int wm = w >> 2, wn = w & 3;
  const int lr = lane & 15, lg = lane >> 4;
  const int bhalf = wn >> 1;

  const int bid = blockIdx.x;
  const int wg = (bid & 7) * 32 + (bid >> 3);
  const int m0 = (wg >> 4) * 256, n0 = (wg & 15) * 256;

  const bf16* gA[2][2];
  const bf16* gB[2][2];
  int ldsOff0, ldsOff1;
  {
    int c0 = (w * 2 + 0) * 64 + lane;
    int c1 = (w * 2 + 1) * 64 + lane;
    int r0 = c0 >> 3, r1 = c1 >> 3;
    int e0 = ((c0 & 7) ^ (r0 & 7)) * 8;
    int e1 = ((c1 & 7) ^ (r1 & 7)) * 8;
    ldsOff0 = c0 * 16; ldsOff1 = c1 * 16;
    gA[0][0] = A + (size_t)(m0 + r0) * K + e0;
    gA[0][1] = A + (size_t)(m0 + r1) * K + e1;
    gA[1][0] = A + (size_t)(m0 + 128 + r0) * K + e0;
    gA[1][1] = A + (size_t)(m0 + 128 + r1) * K + e1;
    gB[0][0] = Bt + (size_t)(n0 + r0) * K + e0;
    gB[0][1] = Bt + (size_t)(n0 + r1) * K + e1;
    gB[1][0] = Bt + (size_t)(n0 + 128 + r0) * K + e0;
    gB[1][1] = Bt + (size_t)(n0 + 128 + r1) * K + e1;
  }

  const int swz = (lr & 7) << 4;
  const int ck0 = (lg * 16) ^ swz;
  const int ck1 = (64 + lg * 16) ^ swz;
  const int aRowB = lr * 128;
  const int bRowB = ((wn & 1) * 64 + lr) * 128;

  f32x4 acc[8][4];
#pragma unroll
  for (int mi = 0; mi < 8; ++mi)
#pragma unroll
    for (int ni = 0; ni < 4; ++ni) acc[mi][ni] = (f32x4){0.f, 0.f, 0.f, 0.f};

  frag8 b00, b01, b10, b11, b20, b21, b30, b31;

  STAGE(1, 0, 0, 0); STAGE(1, 1, 0, 0);
  STAGE(0, 0, 0, 0); STAGE(0, 1, 0, 0);
  STAGE(1, 0, 1, 1); STAGE(1, 1, 1, 1);
  VM4;
  __builtin_amdgcn_s_barrier();

  for (int tt = 0; tt < 62; tt += 2) {
    TILE(tt, 1, 1, VM4);
    TILE(tt + 1, 1, 1, VM4);
  }
  TILE(62, 1, 0, VM0);
  TILE(63, 0, 0, NOW);

#pragma unroll
  for (int mi = 0; mi < 8; ++mi)
#pragma unroll
    for (int ni = 0; ni < 4; ++ni) {
      f32x4 v = acc[mi][ni];
      int col = n0 + wn * 64 + ni * 16 + lr;
      if (ROPE) {
        // rope pair partner is the adjacent column = adjacent lane (lr^1)
        int i = (col & 127) >> 1;
        const bool odd = (col & 1);
#pragma unroll
        for (int ii = 0; ii < 4; ++ii) {
          int row = m0 + wm * 128 + mi * 16 + lg * 4 + ii;
          int s = row & 1023;
          float c = fc[s * 64 + i], si = fs[s * 64 + i];
          float val = v[ii];
          float par = __shfl_xor(val, 1);
          float o = val * c + (odd ? par * si : -par * si);
          storeC(C, (size_t)row * N + col, o);
        }
      } else {
#pragma unroll
        for (int ii = 0; ii < 4; ++ii) {
          int row = m0 + wm * 128 + mi * 16 + lg * 4 + ii;
          storeC(C, (size_t)row * N + col, v[ii]);
        }
      }
    }
}

// ---------------- V transpose: v[b][s][h][d] -> vt[b][h][d][s] ----------------
__global__ __launch_bounds__(256) void transpose_v_kernel(const bf16* __restrict__ v,
                                                          bf16* __restrict__ vt) {
  __shared__ unsigned short tile[32][40];
  const int st = blockIdx.x * 32;
  const int dt = blockIdx.y * 32;
  const int bh = blockIdx.z;
  const int b = bh >> 5, h = bh & 31;
  const int t = threadIdx.x;
  const int r = t >> 3, c4 = (t & 7) * 4;
  const unsigned short* src = reinterpret_cast<const unsigned short*>(v) +
      ((size_t)(b * 1024 + st + r)) * 4096 + h * 128 + dt + c4;
  uint2 d = *reinterpret_cast<const uint2*>(src);
  tile[r][c4 + 0] = (unsigned short)(d.x & 0xffff);
  tile[r][c4 + 1] = (unsigned short)(d.x >> 16);
  tile[r][c4 + 2] = (unsigned short)(d.y & 0xffff);
  tile[r][c4 + 3] = (unsigned short)(d.y >> 16);
  __syncthreads();
  uint2 o;
  o.x = (uint32_t)tile[c4 + 0][r] | ((uint32_t)tile[c4 + 1][r] << 16);
  o.y = (uint32_t)tile[c4 + 2][r] | ((uint32_t)tile[c4 + 3][r] << 16);
  unsigned short* dst = reinterpret_cast<unsigned short*>(vt) +
      ((size_t)bh * 128 + dt + r) * 1024 + st + c4;
  *reinterpret_cast<uint2*>(dst) = o;
}

// ---------------- Flash attention v4b: swapped QK^T + in-register P (no P-LDS) ----------------
// QBLK=128, 8 waves, double-buffered K/V in 64KB LDS -> 2 blocks/CU.
// Lane (lr,lg) holds P[qrow=lr][kc=16ni+4lg+i]. PV A-frag gathered with TWO shfls per word
// (lo/hi word candidates, both wave-uniform) + dest-side select — fixes the R4 bug where the
// source lane evaluated the word index with its own lg.
__global__ __launch_bounds__(512, 4) void attn_kernel(const bf16* __restrict__ q,
                                                      const bf16* __restrict__ k,
                                                      const bf16* __restrict__ vt,
                                                      bf16* __restrict__ out) {
  __shared__ __align__(16) char als[65536];
  const int qt = blockIdx.x, h = blockIdx.y, b = blockIdx.z;
  const int t = threadIdx.x;
  const int lane = t & 63, w = t >> 6;
  const int lr = lane & 15, lg = lane >> 4;
  const int NT = 2 * qt + 2;

  frag8 aq[4];
  {
    const bf16* qp = q + ((size_t)(b * 1024 + qt * 128 + w * 16 + lr)) * 4096 + h * 128 + lg * 8;
#pragma unroll
    for (int ks = 0; ks < 4; ++ks) aq[ks] = *reinterpret_cast<const frag8*>(qp + ks * 32);
  }

  const bf16* kbase = k + (size_t)b * 1024 * 4096 + h * 128;
  const bf16* vbase = vt + ((size_t)(b * 32 + h)) * 128 * 1024;

  const int L0 = t * 16, L1 = (t + 512) * 16;
  const int kr0 = L0 >> 8, kr1 = L1 >> 8;
  const size_t kOff0 = (size_t)kr0 * 4096 + (((L0 & 255) ^ ((kr0 & 7) << 4)) >> 1);
  const size_t kOff1 = (size_t)kr1 * 4096 + (((L1 & 255) ^ ((kr1 & 7) << 4)) >> 1);
  const int vr0 = L0 >> 7, vr1 = L1 >> 7;
  const size_t vOff0 = (size_t)vr0 * 1024 + (((L0 & 127) ^ ((vr0 & 7) << 4)) >> 1);
  const size_t vOff1 = (size_t)vr1 * 1024 + (((L1 & 127) ^ ((vr1 & 7) << 4)) >> 1);

#define STAGE_K(tt, bp) do { char* _d = als + (bp) * 16384;                    \
    gl_lds16(kbase + (size_t)(tt) * 262144 + kOff0, _d + L0);                  \
    gl_lds16(kbase + (size_t)(tt) * 262144 + kOff1, _d + L1); } while (0)
#define STAGE_V(tt, bp) do { char* _d = als + 32768 + (bp) * 16384;            \
    gl_lds16(vbase + (size_t)(tt) * 64 + vOff0, _d + L0);                      \
    gl_lds16(vbase + (size_t)(tt) * 64 + vOff1, _d + L1); } while (0)

  f32x4 oacc[8] = {};
  float mrow = -1e30f, lrow = 0.f;   // lane owns q-row (w*16 + lr)
  const float scale = 0.08838834764831845f;  // 1/sqrt(128)
  const int qmaxw = qt * 128 + w * 16 + 15;
  const int qr_g = qt * 128 + w * 16 + lr;

  STAGE_K(0, 0); STAGE_V(0, 0);
  STAGE_K(1, 1); STAGE_V(1, 1);

  for (int kt = 0; kt < NT; ++kt) {
    const int cur = kt & 1;
    const bool act = (kt * 64 <= qmaxw);
    const bool domask = (kt >= 2 * qt);
    char* Kc = als + cur * 16384;
    char* Vc = als + 32768 + cur * 16384;

    if (kt + 1 < NT) { VM4; } else { VM0; }
    __builtin_amdgcn_s_barrier();

    // S^T = K Q^T: sacc[ni][i] = S[kc=ni*16+lg*4+i][qrow=lr]
    f32x4 sacc[4] = {};
    if (act) {
      __builtin_amdgcn_s_setprio(1);
#pragma unroll
      for (int ks = 0; ks < 4; ++ks) {
#pragma unroll
        for (int ni = 0; ni < 4; ++ni) {
          int n = ni * 16 + lr;
          frag8 bk = *reinterpret_cast<const frag8*>(
              Kc + n * 256 + ((ks * 64 + lg * 16) ^ ((n & 7) << 4)));
          sacc[ni] = MF(bk, aq[ks], sacc[ni]);   // SWAPPED: A=K, B=Q -> S^T
        }
      }
      __builtin_amdgcn_s_setprio(0);
    }
    __builtin_amdgcn_s_barrier();
    if (kt + 2 < NT) STAGE_K(kt + 2, cur);

    if (act) {
#pragma unroll
      for (int ni = 0; ni < 4; ++ni)
#pragma unroll
        for (int i = 0; i < 4; ++i) {
          float x = sacc[ni][i] * scale;
          if (domask) {
            int kc = kt * 64 + ni * 16 + lg * 4 + i;
            if (kc > qr_g) x = -1e30f;
          }
          sacc[ni][i] = x;
        }

      // row softmax: in-register 16-reduce + shfl_xor(16,32)
      float pm = sacc[0][0];
#pragma unroll
      for (int ni = 0; ni < 4; ++ni)
#pragma unroll
        for (int i = 0; i < 4; ++i) pm = fmaxf(pm, sacc[ni][i]);
      pm = fmaxf(pm, __shfl_xor(pm, 16));
      pm = fmaxf(pm, __shfl_xor(pm, 32));
      float mn = fmaxf(mrow, pm);
      float f = __expf(mrow - mn);
      float rs = 0.f;
#pragma unroll
      for (int ni = 0; ni < 4; ++ni)
#pragma unroll
        for (int i = 0; i < 4; ++i) {
          float p = __expf(sacc[ni][i] - mn);
          sacc[ni][i] = p;
          rs += p;
        }
      rs += __shfl_xor(rs, 16);
      rs += __shfl_xor(rs, 32);
      lrow = lrow * f + rs;
      mrow = mn;

      // pack P to bf16x2 words: Wrd[ni*2+jj] covers kc = 16ni+4lg+2jj..+1
      uint32_t Wrd[8];
#pragma unroll
      for (int ni = 0; ni < 4; ++ni)
#pragma unroll
        for (int jj = 0; jj < 2; ++jj) {
          union { uint32_t u; bf16 hh[2]; } pk;
          pk.hh[0] = __float2bfloat16(sacc[ni][2 * jj]);
          pk.hh[1] = __float2bfloat16(sacc[ni][2 * jj + 1]);
          Wrd[ni * 2 + jj] = pk.u;
        }

      // rescale O: row lg*4+i is owned by lane lr=that row
      float fi0 = __shfl(f, lg * 4 + 0);
      float fi1 = __shfl(f, lg * 4 + 1);
      float fi2 = __shfl(f, lg * 4 + 2);
      float fi3 = __shfl(f, lg * 4 + 3);
#pragma unroll
      for (int nj = 0; nj < 8; ++nj) {
        oacc[nj][0] *= fi0; oacc[nj][1] *= fi1;
        oacc[nj][2] *= fi2; oacc[nj][3] *= fi3;
      }

      // O += P V; ap words via in-register shfl gather (no P-LDS).
      // Dest (lr,lg) word j2 needs kc' = ks2*32 + lg*8 + 2*j2 from owner lane
      // (lr, lg' = (2lg + (j2>>1)) & 3). Owner's word index depends on DEST's lg
      // (>=2 or not), so fetch BOTH candidates and select locally.
      __builtin_amdgcn_s_setprio(1);
#pragma unroll
      for (int ks2 = 0; ks2 < 2; ++ks2) {
        union { frag8 fr; uint32_t w[4]; } apu;
#pragma unroll
        for (int j2 = 0; j2 < 4; ++j2) {
          int src = lr + (((2 * lg) + (j2 >> 1)) & 3) * 16;
          uint32_t lo = __shfl(Wrd[4 * ks2 + (j2 & 1)], src);       // dest lg<2
          uint32_t hi = __shfl(Wrd[4 * ks2 + 2 + (j2 & 1)], src);   // dest lg>=2
          apu.w[j2] = (lg & 2) ? hi : lo;
        }
#pragma unroll
        for (int nj = 0; nj < 8; ++nj) {
          int d = nj * 16 + lr;
          frag8 bv = *reinterpret_cast<const frag8*>(
              Vc + d * 128 + ((ks2 * 64 + lg * 16) ^ ((d & 7) << 4)));
          oacc[nj] = MF(apu.fr, bv, oacc[nj]);
        }
      }
      __builtin_amdgcn_s_setprio(0);
    }
    __builtin_amdgcn_s_barrier();
    if (kt + 2 < NT) STAGE_V(kt + 2, cur);
  }

  float lv0 = __shfl(lrow, lg * 4 + 0);
  float lv1 = __shfl(lrow, lg * 4 + 1);
  float lv2 = __shfl(lrow, lg * 4 + 2);
  float lv3 = __shfl(lrow, lg * 4 + 3);
#pragma unroll
  for (int nj = 0; nj < 8; ++nj) {
    int srow0 = qt * 128 + w * 16 + lg * 4;
    size_t base = ((size_t)(b * 1024 + srow0)) * 4096 + h * 128 + nj * 16 + lr;
    out[base]          = __float2bfloat16(oacc[nj][0] / lv0);
    out[base + 4096]   = __float2bfloat16(oacc[nj][1] / lv1);
    out[base + 8192]   = __float2bfloat16(oacc[nj][2] / lv2);
    out[base + 12288]  = __float2bfloat16(oacc[nj][3] / lv3);
  }
#undef STAGE_K
#undef STAGE_V
}

// ---------------- host launch ----------------
extern "C" void kernel_launch(void* const* d_in, const int* in_sizes, int n_in,
                              void* d_out, int out_size, void* d_ws, size_t ws_size,
                              hipStream_t stream) {
  const float* x  = (const float*)d_in[0];
  const float* fc = (const float*)d_in[2];
  const float* fs = (const float*)d_in[3];
  const float* wq = (const float*)d_in[5];
  const float* wk = (const float*)d_in[6];
  const float* wv = (const float*)d_in[7];
  const float* wo = (const float*)d_in[8];
  float* out = (float*)d_out;

  const size_t SZ = (size_t)4096 * 4096 * 2;
  char* w = (char*)d_ws;
  bf16* xb = (bf16*)(w);
  bf16* wb = (bf16*)(w + SZ);
  bf16* qb = (bf16*)(w + 2 * SZ);
  bf16* kb = (bf16*)(w + 3 * SZ);
  bf16* vb = (bf16*)(w + 4 * SZ);
  bf16* vtb = xb;  // xb dead after QKV GEMMs
  bf16* ao  = vb;  // vb dead after transpose

  const int n8 = 4096 * 4096 / 8;
  dim3 cgrd(n8 / 256), blk(256);
  dim3 ggrd(256);
  dim3 gblk(512);

  conv_kernel<<<cgrd, blk, 0, stream>>>(x, xb, n8);
  conv_kernel<<<cgrd, blk, 0, stream>>>(wq, wb, n8);
  gemm8<bf16, true><<<ggrd, gblk, 0, stream>>>(xb, wb, qb, fc, fs);   // +RoPE
  conv_kernel<<<cgrd, blk, 0, stream>>>(wk, wb, n8);
  gemm8<bf16, true><<<ggrd, gblk, 0, stream>>>(xb, wb, kb, fc, fs);   // +RoPE
  conv_kernel<<<cgrd, blk, 0, stream>>>(wv, wb, n8);
  gemm8<bf16, false><<<ggrd, gblk, 0, stream>>>(xb, wb, vb, fc, fs);
  transpose_v_kernel<<<dim3(32, 4, 128), blk, 0, stream>>>(vb, vtb);
  attn_kernel<<<dim3(8, 32, 4), gblk, 0, stream>>>(qb, kb, vtb, ao);
  conv_kernel<<<cgrd, blk, 0, stream>>>(wo, wb, n8);
  gemm8<float, false><<<ggrd, gblk, 0, stream>>>(ao, wb, out, fc, fs);
}